// Round 8
// baseline (307.070 us; speedup 1.0000x reference)
//
#include <hip/hip_runtime.h>
#include <hip/hip_bf16.h>
#include <math.h>

#define NDIM 256
#define HDIM 32
#define SCB 512

typedef __attribute__((ext_vector_type(8))) short bf16x8;
typedef __attribute__((ext_vector_type(4))) float f32x4;
typedef __attribute__((ext_vector_type(2))) float f32x2;
typedef unsigned long long ull;

// ---------- bf16 helpers ----------
__device__ inline float bf2f(unsigned short u) {
  union { unsigned int i; float f; } c; c.i = ((unsigned int)u) << 16; return c.f;
}
__device__ inline unsigned short f2bf(float f) {
  union { float f; unsigned int i; } c; c.f = f;
  unsigned int x = c.i;
  unsigned int lsb = (x >> 16) & 1u;
  x += 0x7fffu + lsb;
  return (unsigned short)(x >> 16);
}
__device__ inline float4 ldbf4(const unsigned short* p) {
  ull raw = *(const ull*)p;
  float4 f;
  f.x = bf2f((unsigned short)(raw));
  f.y = bf2f((unsigned short)(raw >> 16));
  f.z = bf2f((unsigned short)(raw >> 32));
  f.w = bf2f((unsigned short)(raw >> 48));
  return f;
}
__device__ inline void stbf4(unsigned short* p, float4 v) {
  ull raw = (ull)f2bf(v.x) | ((ull)f2bf(v.y) << 16)
          | ((ull)f2bf(v.z) << 32) | ((ull)f2bf(v.w) << 48);
  *(ull*)p = raw;
}
__device__ inline ull pk4_bf16(float v0, float v1, float v2, float v3) {
  return (ull)f2bf(v0) | ((ull)f2bf(v1) << 16) | ((ull)f2bf(v2) << 32) | ((ull)f2bf(v3) << 48);
}

// ---------- fp8 e4m3 helpers ----------
__device__ inline unsigned char f2e4m3(float v) {
#if __has_builtin(__builtin_amdgcn_cvt_pk_fp8_f32)
  return (unsigned char)(__builtin_amdgcn_cvt_pk_fp8_f32(v, v, 0, false) & 0xff);
#else
  union { float f; unsigned int u; } c; c.f = v;
  unsigned char s = (unsigned char)((c.u >> 24) & 0x80);
  float a = fabsf(v);
  if (!(a < 448.f)) return (unsigned char)(s | 0x7e);
  if (a < 0.0009765625f) return s;
  int e = (int)((c.u >> 23) & 0xff) - 127;
  if (e < -6) {
    int q = (int)rintf(ldexpf(a, 9));
    if (q >= 8) return (unsigned char)(s | 0x08);
    return (unsigned char)(s | q);
  }
  int q = (int)rintf(ldexpf(a, 3 - e));
  if (q == 16) { e++; q = 8; }
  if (e > 8) return (unsigned char)(s | 0x7e);
  return (unsigned char)(s | ((e + 7) << 3) | (q - 8));
#endif
}
__device__ inline unsigned int pk4_e4m3(float v0, float v1, float v2, float v3) {
#if __has_builtin(__builtin_amdgcn_cvt_pk_fp8_f32)
  int w = __builtin_amdgcn_cvt_pk_fp8_f32(v0, v1, 0, false);
  w = __builtin_amdgcn_cvt_pk_fp8_f32(v2, v3, w, true);
  return (unsigned int)w;
#else
  return (unsigned int)f2e4m3(v0) | ((unsigned int)f2e4m3(v1) << 8)
       | ((unsigned int)f2e4m3(v2) << 16) | ((unsigned int)f2e4m3(v3) << 24);
#endif
}
template<bool HI>
__device__ inline f32x2 e4m3pk(unsigned int w) {
#if __has_builtin(__builtin_amdgcn_cvt_pk_f32_fp8)
  return __builtin_amdgcn_cvt_pk_f32_fp8((int)w, HI);
#else
  unsigned int h = HI ? (w >> 16) : w;
  f32x2 r;
  #pragma unroll
  for (int j = 0; j < 2; ++j) {
    unsigned char b = (unsigned char)(h >> (8 * j));
    int e = (b >> 3) & 0xf, mm = b & 7;
    float val = e ? ldexpf((float)(8 + mm), e - 10) : ldexpf((float)mm, -9);
    r[j] = (b & 0x80) ? -val : val;
  }
  return r;
#endif
}

// ---------- fp32 -> bf16 bulk convert ----------
__global__ void xconv_k(const float* __restrict__ x, unsigned short* __restrict__ xb, int n8) {
  int i = blockIdx.x * 256 + threadIdx.x;
  if (i >= n8) return;
  const float* p = x + (size_t)i * 8;
  float4 a = *(const float4*)p;
  float4 b = *(const float4*)(p + 4);
  ull lo = (ull)f2bf(a.x) | ((ull)f2bf(a.y) << 16) | ((ull)f2bf(a.z) << 32) | ((ull)f2bf(a.w) << 48);
  ull hi = (ull)f2bf(b.x) | ((ull)f2bf(b.y) << 16) | ((ull)f2bf(b.z) << 32) | ((ull)f2bf(b.w) << 48);
  ull* d = (ull*)(xb + (size_t)i * 8);
  d[0] = lo; d[1] = hi;
}

// ---------- weight transpose + bf16: Wt[n][k] = bf16(W[k][n]) ----------
__global__ void wconv_k(const float* __restrict__ W, unsigned short* __restrict__ Wt,
                        int K, int Ncol) {
  int idx = blockIdx.x * 256 + threadIdx.x;
  if (idx < K * Ncol) {
    int n = idx / K;
    int k = idx - n * K;
    Wt[idx] = f2bf(W[(size_t)k * Ncol + n]);
  }
}

// ---------- Wqkv transpose + bf16 + column permutation ----------
__global__ void wconvqkv_k(const float* __restrict__ W, unsigned short* __restrict__ Wt) {
  int idx = blockIdx.x * 256 + threadIdx.x;   // over 768*256
  if (idx >= 768 * 256) return;
  int j = idx >> 8;          // out col 0..767
  int k = idx & 255;
  int seg = j >> 8;
  int jj = j & 255;
  int h = jj >> 5, t = jj & 31;
  int orig = h * 96 + seg * 32 + t;
  Wt[(size_t)j * 256 + k] = f2bf(W[(size_t)k * 768 + orig]);
}

// ---------- fused-FFN weight build ----------
// wf[n][k] (ld 512): k<256 -> bf16(W1[k][n]);  k=256+a -> bf16(sum_j Wout[a][j]*W1[256+j][n])
__global__ void wf1_k(const float* __restrict__ W1, unsigned short* __restrict__ wf) {
  int idx = blockIdx.x * 256 + threadIdx.x;   // over 256*256
  if (idx >= 256 * 256) return;
  int n = idx >> 8, k = idx & 255;
  wf[(size_t)n * 512 + k] = f2bf(W1[(size_t)k * 256 + n]);
}
__global__ void wfc_k(const float* __restrict__ Wout, const float* __restrict__ W1,
                      unsigned short* __restrict__ wf) {
  int idx = blockIdx.x * 256 + threadIdx.x;   // over 256*256
  if (idx >= 256 * 256) return;
  int a = idx >> 8, n = idx & 255;            // a block-uniform (broadcast), n coalesced
  float s = 0.f;
  #pragma unroll 4
  for (int j = 0; j < 256; ++j)
    s += Wout[(size_t)a * 256 + j] * W1[(size_t)(256 + j) * 256 + n];
  wf[(size_t)n * 512 + 256 + a] = f2bf(s);
}
__global__ void bfc_k(const float* __restrict__ bout, const float* __restrict__ b1,
                      const float* __restrict__ W1, float* __restrict__ bc) {
  int n = threadIdx.x;
  float s = b1[n];
  for (int j = 0; j < 256; ++j)
    s += bout[j] * W1[(size_t)(256 + j) * 256 + n];
  bc[n] = s;
}

// ---------- CSR build ----------
__global__ void hist_k(const int* __restrict__ dst, int* __restrict__ deg, int E) {
  int e = blockIdx.x * 256 + threadIdx.x;
  if (e < E) atomicAdd(&deg[dst[e]], 1);
}

__global__ __launch_bounds__(SCB) void bsum_k(const int* __restrict__ deg, int* __restrict__ bsum, int n) {
  int tid = threadIdx.x;
  int i = blockIdx.x * SCB + tid;
  int v = (i < n) ? deg[i] : 0;
  #pragma unroll
  for (int d = 1; d < 64; d <<= 1) v += __shfl_xor(v, d);
  __shared__ int wsum[8];
  if ((tid & 63) == 0) wsum[tid >> 6] = v;
  __syncthreads();
  if (tid == 0) {
    int s = 0;
    #pragma unroll
    for (int j = 0; j < 8; ++j) s += wsum[j];
    bsum[blockIdx.x] = s;
  }
}

__global__ __launch_bounds__(128) void bscan_k(int* __restrict__ bsum, int nb) {
  __shared__ int tmp[128];
  int tid = threadIdx.x;
  int v = (tid < nb) ? bsum[tid] : 0;
  tmp[tid] = v;
  __syncthreads();
  for (int d = 1; d < 128; d <<= 1) {
    int t = (tid >= d) ? tmp[tid - d] : 0;
    __syncthreads();
    tmp[tid] += t;
    __syncthreads();
  }
  if (tid < nb) bsum[tid] = tmp[tid];
}

__global__ __launch_bounds__(SCB) void offs_k(const int* __restrict__ deg, const int* __restrict__ bsum,
                                              int* __restrict__ offs, int n) {
  int tid = threadIdx.x, lane = tid & 63, wid = tid >> 6;
  int b = blockIdx.x;
  int i = b * SCB + tid;
  int v = (i < n) ? deg[i] : 0;
  int incl = v;
  #pragma unroll
  for (int d = 1; d < 64; d <<= 1) { int t = __shfl_up(incl, d); if (lane >= d) incl += t; }
  __shared__ int wsum[8];
  if (lane == 63) wsum[wid] = incl;
  __syncthreads();
  if (tid < 8) {
    int s = wsum[tid];
    #pragma unroll
    for (int d = 1; d < 8; d <<= 1) { int t = __shfl_up(s, d); if (tid >= d) s += t; }
    wsum[tid] = s;
  }
  __syncthreads();
  int base = (b > 0 ? bsum[b - 1] : 0) + (wid > 0 ? wsum[wid - 1] : 0);
  if (i < n) offs[i] = base + incl - v;
  if (i == n - 1) offs[n] = base + incl;
}

__global__ void scatter_k(const int* __restrict__ src, const int* __restrict__ dst,
                          int* __restrict__ cursor, int* __restrict__ ssrc, int E) {
  int e = blockIdx.x * 256 + threadIdx.x;
  if (e < E) {
    int p = atomicAdd(&cursor[dst[e]], 1);
    ssrc[p] = src[e];
  }
}

// ---------- per-node softmax attention, fp8 K/V, fixed-shift ----------
__global__ __launch_bounds__(256) void attn_k(
    const unsigned short* Q,
    const unsigned char* __restrict__ K8,
    const unsigned char* __restrict__ V8,
    const int* __restrict__ offs,
    const int* __restrict__ ssrc,
    unsigned short* agg, int N)
{
  int n = blockIdx.x * 4 + (threadIdx.x >> 6);
  if (n >= N) return;
  int lane = threadIdx.x & 63;
  int col = lane << 2;
  const float scale = 0.17677669529663689f;
  float4 q4 = ldbf4(Q + (size_t)n * NDIM + col);
  q4.x *= scale; q4.y *= scale; q4.z *= scale; q4.w *= scale;
  int e0 = offs[n], e1 = offs[n + 1];
  float den = 0.f;
  float ax = 0.f, ay = 0.f, az = 0.f, aw = 0.f;
  int e = e0;
  for (; e + 8 <= e1; e += 8) {
    unsigned int kw[8], vw[8];
    #pragma unroll
    for (int j = 0; j < 8; ++j) {
      int s = ssrc[e + j];
      kw[j] = *(const unsigned int*)(K8 + (size_t)s * NDIM + col);
      vw[j] = *(const unsigned int*)(V8 + (size_t)s * NDIM + col);
    }
    float d[8];
    #pragma unroll
    for (int j = 0; j < 8; ++j) {
      f32x2 k01 = e4m3pk<false>(kw[j]);
      f32x2 k23 = e4m3pk<true>(kw[j]);
      d[j] = q4.x * k01[0] + q4.y * k01[1] + q4.z * k23[0] + q4.w * k23[1];
    }
    #pragma unroll
    for (int j = 0; j < 8; ++j) {
      d[j] += __shfl_xor(d[j], 1);
      d[j] += __shfl_xor(d[j], 2);
      d[j] += __shfl_xor(d[j], 4);
    }
    #pragma unroll
    for (int j = 0; j < 8; ++j) {
      float p = __expf(d[j]);
      den += p;
      f32x2 v01 = e4m3pk<false>(vw[j]);
      f32x2 v23 = e4m3pk<true>(vw[j]);
      ax += p * v01[0]; ay += p * v01[1];
      az += p * v23[0]; aw += p * v23[1];
    }
  }
  for (; e + 4 <= e1; e += 4) {
    unsigned int kw[4], vw[4];
    #pragma unroll
    for (int j = 0; j < 4; ++j) {
      int s = ssrc[e + j];
      kw[j] = *(const unsigned int*)(K8 + (size_t)s * NDIM + col);
      vw[j] = *(const unsigned int*)(V8 + (size_t)s * NDIM + col);
    }
    float d[4];
    #pragma unroll
    for (int j = 0; j < 4; ++j) {
      f32x2 k01 = e4m3pk<false>(kw[j]);
      f32x2 k23 = e4m3pk<true>(kw[j]);
      d[j] = q4.x * k01[0] + q4.y * k01[1] + q4.z * k23[0] + q4.w * k23[1];
    }
    #pragma unroll
    for (int j = 0; j < 4; ++j) {
      d[j] += __shfl_xor(d[j], 1);
      d[j] += __shfl_xor(d[j], 2);
      d[j] += __shfl_xor(d[j], 4);
    }
    #pragma unroll
    for (int j = 0; j < 4; ++j) {
      float p = __expf(d[j]);
      den += p;
      f32x2 v01 = e4m3pk<false>(vw[j]);
      f32x2 v23 = e4m3pk<true>(vw[j]);
      ax += p * v01[0]; ay += p * v01[1];
      az += p * v23[0]; aw += p * v23[1];
    }
  }
  for (; e < e1; ++e) {
    int s = ssrc[e];
    unsigned int kw = *(const unsigned int*)(K8 + (size_t)s * NDIM + col);
    unsigned int vw = *(const unsigned int*)(V8 + (size_t)s * NDIM + col);
    f32x2 k01 = e4m3pk<false>(kw);
    f32x2 k23 = e4m3pk<true>(kw);
    float d = q4.x * k01[0] + q4.y * k01[1] + q4.z * k23[0] + q4.w * k23[1];
    d += __shfl_xor(d, 1);
    d += __shfl_xor(d, 2);
    d += __shfl_xor(d, 4);
    float p = __expf(d);
    den += p;
    f32x2 v01 = e4m3pk<false>(vw);
    f32x2 v23 = e4m3pk<true>(vw);
    ax += p * v01[0]; ay += p * v01[1];
    az += p * v23[0]; aw += p * v23[1];
  }
  float inv = (den > 0.f) ? 1.f / den : 0.f;
  stbf4(agg + (size_t)n * NDIM + col, make_float4(ax * inv, ay * inv, az * inv, aw * inv));
}

// ---------- QKV MFMA GEMM (unchanged structure from R7) ----------
__global__ __launch_bounds__(256, 4) void qkvgemm_k(
    const unsigned short* __restrict__ A1,
    const unsigned short* __restrict__ Wt, const float* __restrict__ bias,
    unsigned short* __restrict__ Oq, unsigned char* __restrict__ Ok, unsigned char* __restrict__ Ov,
    int M, int nct)
{
  __shared__ unsigned short As[128 * 64];
  __shared__ unsigned short Bs[128 * 64];
  const int tid = threadIdx.x;
  const int lane = tid & 63;
  const int wid = tid >> 6;

  const int nwg = gridDim.x;
  const int q8 = nwg >> 3, r8 = nwg & 7;
  const int xcd = blockIdx.x & 7, idx8 = blockIdx.x >> 3;
  const int swz = (xcd < r8 ? xcd * (q8 + 1) : r8 * (q8 + 1) + (xcd - r8) * q8) + idx8;
  const int bmt = swz / nct;
  const int bnt = swz - bmt * nct;
  const int bm = bmt * 128;
  const int bn = bnt * 128;

  const int wr = (wid >> 1) << 6;
  const int wc = (wid & 1) << 6;
  const int l15 = lane & 15, lhi = lane >> 4;
  const int srow = lane >> 3;
  const int ssl = (((lane & 7) ^ (lane >> 3)) << 3);

  f32x4 acc[4][4];
  #pragma unroll
  for (int i = 0; i < 4; ++i)
    #pragma unroll
    for (int j = 0; j < 4; ++j) acc[i][j] = (f32x4){0.f, 0.f, 0.f, 0.f};

  for (int k0 = 0; k0 < 256; k0 += 64) {
    #pragma unroll
    for (int t = 0; t < 4; ++t) {
      int qi = wid * 4 + t;
      const unsigned short* ga = A1 + (size_t)(bm + qi * 8 + srow) * 256 + k0 + ssl;
      __builtin_amdgcn_global_load_lds(
          (const __attribute__((address_space(1))) void*)ga,
          (__attribute__((address_space(3))) void*)&As[qi * 512], 16, 0, 0);
      const unsigned short* gb = Wt + (size_t)(bn + qi * 8 + srow) * 256 + k0 + ssl;
      __builtin_amdgcn_global_load_lds(
          (const __attribute__((address_space(1))) void*)gb,
          (__attribute__((address_space(3))) void*)&Bs[qi * 512], 16, 0, 0);
    }
    __syncthreads();
    #pragma unroll
    for (int kk = 0; kk < 64; kk += 32) {
      bf16x8 af[4], bfr[4];
      #pragma unroll
      for (int mi = 0; mi < 4; ++mi) {
        int rA = wr + mi * 16 + l15;
        af[mi] = *(const bf16x8*)&As[rA * 64 + ((((kk >> 3) + lhi) ^ (rA & 7)) << 3)];
      }
      #pragma unroll
      for (int ni = 0; ni < 4; ++ni) {
        int rB = wc + ni * 16 + l15;
        bfr[ni] = *(const bf16x8*)&Bs[rB * 64 + ((((kk >> 3) + lhi) ^ (rB & 7)) << 3)];
      }
      #pragma unroll
      for (int mi = 0; mi < 4; ++mi)
        #pragma unroll
        for (int ni = 0; ni < 4; ++ni)
          acc[mi][ni] = __builtin_amdgcn_mfma_f32_16x16x32_bf16(bfr[ni], af[mi], acc[mi][ni], 0, 0, 0);
    }
    __syncthreads();
  }

  #pragma unroll
  for (int ni = 0; ni < 4; ++ni) {
    const int gc0 = bn + wc + ni * 16 + (lhi << 2);
    int seg = gc0 >> 8, jj0 = gc0 & 255;
    int h = jj0 >> 5, t0 = jj0 & 31;
    float4 bb = *(const float4*)&bias[h * 96 + seg * 32 + t0];
    #pragma unroll
    for (int mi = 0; mi < 4; ++mi) {
      int gr = bm + wr + mi * 16 + l15;
      if (gr >= M) continue;
      float v0 = acc[mi][ni][0] + bb.x;
      float v1 = acc[mi][ni][1] + bb.y;
      float v2 = acc[mi][ni][2] + bb.z;
      float v3 = acc[mi][ni][3] + bb.w;
      if (seg == 0) {
        *(ull*)&Oq[(size_t)gr * NDIM + jj0] = pk4_bf16(v0, v1, v2, v3);
      } else {
        unsigned int w = pk4_e4m3(v0, v1, v2, v3);
        unsigned char* dstp = (seg == 1) ? Ok : Ov;
        *(unsigned int*)&dstp[(size_t)gr * NDIM + jj0] = w;
      }
    }
  }
}

// ---------- FUSED FFN: out = gelu([xb|agg] @ wft + bc) @ W2 + b2 ----------
// BM=64 rows/block, 4 waves (wave wid owns cols wid*64..+63 in both phases).
// Phase1: K=512 (xb 256 | agg 256), h (64x256 bf16) kept in swizzled LDS.
// Phase2: h @ w2t (K2=256, 4 chunks, per-wave private W2 stage, barrier-free).
__global__ __launch_bounds__(256, 2) void ffn_k(
    const unsigned short* __restrict__ xb, const unsigned short* __restrict__ agg,
    const unsigned short* __restrict__ wft, const float* __restrict__ bc,
    const unsigned short* __restrict__ w2t, const float* __restrict__ b2,
    float* __restrict__ out, int M)
{
  __shared__ char smem[73728];
  unsigned short* As1 = (unsigned short*)smem;            // 8 KB  (64x64)
  unsigned short* Bs1 = (unsigned short*)(smem + 8192);   // 32 KB (256x64)
  unsigned short* Bs2 = (unsigned short*)smem;            // 32 KB union (4x 64x64)
  unsigned short* hS  = (unsigned short*)(smem + 40960);  // 32 KB (64x256)

  const int tid = threadIdx.x;
  const int lane = tid & 63;
  const int wid = tid >> 6;
  const int bm = blockIdx.x * 64;
  const int wc = wid << 6;
  const int l15 = lane & 15, lhi = lane >> 4;
  const int srow = lane >> 3;
  const int ssl = (((lane & 7) ^ (lane >> 3)) << 3);

  f32x4 acc[4][4];
  #pragma unroll
  for (int i = 0; i < 4; ++i)
    #pragma unroll
    for (int j = 0; j < 4; ++j) acc[i][j] = (f32x4){0.f, 0.f, 0.f, 0.f};

  // ---- phase 1: h = gelu([xb|agg] @ wft + bc) ----
  for (int k0 = 0; k0 < 512; k0 += 64) {
    const unsigned short* Ab = (k0 < 256) ? xb : agg;
    int ks = k0 & 255;
    #pragma unroll
    for (int t = 0; t < 2; ++t) {
      int qi = wid * 2 + t;   // 0..7 (8-row groups of A)
      const unsigned short* ga = Ab + (size_t)(bm + qi * 8 + srow) * 256 + ks + ssl;
      __builtin_amdgcn_global_load_lds(
          (const __attribute__((address_space(1))) void*)ga,
          (__attribute__((address_space(3))) void*)&As1[qi * 512], 16, 0, 0);
    }
    #pragma unroll
    for (int t = 0; t < 8; ++t) {
      int qi = wid * 8 + t;   // 0..31 (8-row groups of B: 256 outcols)
      const unsigned short* gb = wft + (size_t)(qi * 8 + srow) * 512 + k0 + ssl;
      __builtin_amdgcn_global_load_lds(
          (const __attribute__((address_space(1))) void*)gb,
          (__attribute__((address_space(3))) void*)&Bs1[qi * 512], 16, 0, 0);
    }
    __syncthreads();
    #pragma unroll
    for (int kk = 0; kk < 64; kk += 32) {
      bf16x8 af[4], bfr[4];
      #pragma unroll
      for (int mi = 0; mi < 4; ++mi) {
        int rA = mi * 16 + l15;
        af[mi] = *(const bf16x8*)&As1[rA * 64 + ((((kk >> 3) + lhi) ^ (rA & 7)) << 3)];
      }
      #pragma unroll
      for (int ni = 0; ni < 4; ++ni) {
        int rB = wc + ni * 16 + l15;
        bfr[ni] = *(const bf16x8*)&Bs1[rB * 64 + ((((kk >> 3) + lhi) ^ (rB & 7)) << 3)];
      }
      #pragma unroll
      for (int mi = 0; mi < 4; ++mi)
        #pragma unroll
        for (int ni = 0; ni < 4; ++ni)
          acc[mi][ni] = __builtin_amdgcn_mfma_f32_16x16x32_bf16(bfr[ni], af[mi], acc[mi][ni], 0, 0, 0);
    }
    __syncthreads();
  }

  // gelu + write h to swizzled LDS: lane holds h[mi*16+l15][wc+ni*16+lhi*4 .. +3]
  #pragma unroll
  for (int ni = 0; ni < 4; ++ni) {
    int col0 = wc + ni * 16 + (lhi << 2);
    float4 bb = *(const float4*)&bc[col0];
    #pragma unroll
    for (int mi = 0; mi < 4; ++mi) {
      int row = mi * 16 + l15;
      float v0 = acc[mi][ni][0] + bb.x;
      float v1 = acc[mi][ni][1] + bb.y;
      float v2 = acc[mi][ni][2] + bb.z;
      float v3 = acc[mi][ni][3] + bb.w;
      v0 = 0.5f * v0 * (1.0f + erff(v0 * 0.70710678118654752f));
      v1 = 0.5f * v1 * (1.0f + erff(v1 * 0.70710678118654752f));
      v2 = 0.5f * v2 * (1.0f + erff(v2 * 0.70710678118654752f));
      v3 = 0.5f * v3 * (1.0f + erff(v3 * 0.70710678118654752f));
      int slot = col0 >> 3;
      int swslot = (slot & ~7) | ((slot ^ row) & 7);
      *(ull*)&hS[row * 256 + swslot * 8 + (col0 & 7)] = pk4_bf16(v0, v1, v2, v3);
    }
  }
  __syncthreads();   // h visible to all waves (phase-1 staging buffers now dead)

  // ---- phase 2: out = h @ w2t + b2 (per-wave, barrier-free) ----
  f32x4 acc2[4][4];
  #pragma unroll
  for (int i = 0; i < 4; ++i)
    #pragma unroll
    for (int j = 0; j < 4; ++j) acc2[i][j] = (f32x4){0.f, 0.f, 0.f, 0.f};

  for (int c = 0; c < 4; ++c) {
    #pragma unroll
    for (int t = 0; t < 8; ++t) {
      const unsigned short* gb = w2t + (size_t)(wc + t * 8 + srow) * 256 + c * 64 + ssl;
      __builtin_amdgcn_global_load_lds(
          (const __attribute__((address_space(1))) void*)gb,
          (__attribute__((address_space(3))) void*)&Bs2[wid * 4096 + t * 512], 16, 0, 0);
    }
    asm volatile("s_waitcnt vmcnt(0)" ::: "memory");
    __builtin_amdgcn_sched_barrier(0);
    #pragma unroll
    for (int kk = 0; kk < 64; kk += 32) {
      bf16x8 af[4], bfr[4];
      #pragma unroll
      for (int mi = 0; mi < 4; ++mi) {
        int row = mi * 16 + l15;
        int s = c * 8 + ((((kk >> 3) + lhi) ^ (row & 7)));
        af[mi] = *(const bf16x8*)&hS[row * 256 + (s << 3)];
      }
      #pragma unroll
      for (int ni = 0; ni < 4; ++ni) {
        int rb = ni * 16 + l15;
        bfr[ni] = *(const bf16x8*)&Bs2[wid * 4096 + rb * 64 + ((((kk >> 3) + lhi) ^ (rb & 7)) << 3)];
      }
      #pragma unroll
      for (int mi = 0; mi < 4; ++mi)
        #pragma unroll
        for (int ni = 0; ni < 4; ++ni)
          acc2[mi][ni] = __builtin_amdgcn_mfma_f32_16x16x32_bf16(bfr[ni], af[mi], acc2[mi][ni], 0, 0, 0);
    }
  }

  #pragma unroll
  for (int ni = 0; ni < 4; ++ni) {
    int oc0 = wc + ni * 16 + (lhi << 2);
    float4 bb = *(const float4*)&b2[oc0];
    #pragma unroll
    for (int mi = 0; mi < 4; ++mi) {
      int gr = bm + mi * 16 + l15;
      if (gr >= M) continue;
      *(float4*)&out[(size_t)gr * 256 + oc0] = make_float4(
          acc2[mi][ni][0] + bb.x, acc2[mi][ni][1] + bb.y,
          acc2[mi][ni][2] + bb.z, acc2[mi][ni][3] + bb.w);
    }
  }
}

extern "C" void kernel_launch(void* const* d_in, const int* in_sizes, int n_in,
                              void* d_out, int out_size, void* d_ws, size_t ws_size,
                              hipStream_t stream) {
  (void)n_in; (void)out_size; (void)ws_size;
  const float* x    = (const float*)d_in[0];
  const int*   src  = (const int*)d_in[1];
  const int*   dst  = (const int*)d_in[2];
  const float* Wqkv = (const float*)d_in[3];
  const float* bqkv = (const float*)d_in[4];
  const float* Wout = (const float*)d_in[5];
  const float* bout = (const float*)d_in[6];
  const float* W1   = (const float*)d_in[7];
  const float* b1   = (const float*)d_in[8];
  const float* W2   = (const float*)d_in[9];
  const float* b2   = (const float*)d_in[10];
  float* out = (float*)d_out;

  const int N = in_sizes[0] / NDIM;   // 50000
  const int E = in_sizes[1];          // 800000
  const int Mp = (N + 127) & ~127;    // 50048
  const int nb = (N + SCB - 1) / SCB;

  char* ws = (char*)d_ws;
  size_t off = 0;
  auto alloc = [&](size_t bytes) -> char* {
    char* p = ws + off;
    off += (bytes + 255) & ~(size_t)255;
    return p;
  };
  unsigned short* xb   = (unsigned short*)alloc((size_t)Mp * NDIM * 2);
  unsigned short* Q    = (unsigned short*)alloc((size_t)Mp * NDIM * 2);
  unsigned short* Kb   = (unsigned short*)alloc((size_t)Mp * NDIM * 2);
  unsigned short* Vb   = (unsigned short*)alloc((size_t)Mp * NDIM * 2);
  unsigned short* wqkvt = (unsigned short*)alloc((size_t)768 * 256 * 2);
  unsigned short* wft   = (unsigned short*)alloc((size_t)256 * 512 * 2);
  unsigned short* w2t   = (unsigned short*)alloc((size_t)256 * 256 * 2);
  float*          bc    = (float*)alloc(256 * 4);
  int* deg    = (int*)alloc((size_t)N * 4);
  int* offs   = (int*)alloc((size_t)(N + 1) * 4);
  int* cursor = (int*)alloc((size_t)N * 4);
  int* ssrc   = (int*)alloc((size_t)E * 4);
  int* bsum   = (int*)alloc((size_t)nb * 4);

  unsigned char* K8 = (unsigned char*)Kb;
  unsigned char* V8 = (unsigned char*)Vb;
  unsigned short* agg = Q;    // attn writes in place over Q

  // input/weight prep
  xconv_k<<<(N * NDIM / 8 + 255) / 256, 256, 0, stream>>>(x, xb, N * NDIM / 8);
  wconvqkv_k<<<(768 * 256 + 255) / 256, 256, 0, stream>>>(Wqkv, wqkvt);
  wf1_k<<<256, 256, 0, stream>>>(W1, wft);
  wfc_k<<<256, 256, 0, stream>>>(Wout, W1, wft);
  bfc_k<<<1, 256, 0, stream>>>(bout, b1, W1, bc);
  wconv_k<<<(256 * 256 + 255) / 256, 256, 0, stream>>>(W2, w2t, 256, 256);

  // CSR build
  hipMemsetAsync(deg, 0, (size_t)N * 4, stream);
  hist_k<<<(E + 255) / 256, 256, 0, stream>>>(dst, deg, E);
  bsum_k<<<nb, SCB, 0, stream>>>(deg, bsum, N);
  bscan_k<<<1, 128, 0, stream>>>(bsum, nb);
  offs_k<<<nb, SCB, 0, stream>>>(deg, bsum, offs, N);
  hipMemcpyAsync(cursor, offs, (size_t)N * 4, hipMemcpyDeviceToDevice, stream);
  scatter_k<<<(E + 255) / 256, 256, 0, stream>>>(src, dst, cursor, ssrc, E);

  const int mt = Mp / 128;   // 391

  // QKV projection -> Q (bf16), K8/V8 (fp8); wqkvt column-permuted
  qkvgemm_k<<<mt * 6, 256, 0, stream>>>(
      xb, wqkvt, bqkv, Q, K8, V8, N, 6);

  // edge-softmax aggregation (agg == Q in place)
  attn_k<<<(N + 3) / 4, 256, 0, stream>>>(Q, K8, V8, offs, ssrc, agg, N);

  // fused FFN + W2 -> out (fp32)
  ffn_k<<<Mp / 64, 256, 0, stream>>>(
      xb, agg, wft, bc, w2t, b2, out, N);
}

// Round 9
// 295.674 us; speedup vs baseline: 1.0385x; 1.0385x over previous
//
#include <hip/hip_runtime.h>
#include <hip/hip_bf16.h>
#include <math.h>

#define NDIM 256
#define HDIM 32
#define SCB 512

typedef __attribute__((ext_vector_type(8))) short bf16x8;
typedef __attribute__((ext_vector_type(4))) float f32x4;
typedef __attribute__((ext_vector_type(2))) float f32x2;
typedef unsigned long long ull;

// ---------- bf16 helpers ----------
__device__ inline float bf2f(unsigned short u) {
  union { unsigned int i; float f; } c; c.i = ((unsigned int)u) << 16; return c.f;
}
__device__ inline unsigned short f2bf(float f) {
  union { float f; unsigned int i; } c; c.f = f;
  unsigned int x = c.i;
  unsigned int lsb = (x >> 16) & 1u;
  x += 0x7fffu + lsb;
  return (unsigned short)(x >> 16);
}
__device__ inline float4 ldbf4(const unsigned short* p) {
  ull raw = *(const ull*)p;
  float4 f;
  f.x = bf2f((unsigned short)(raw));
  f.y = bf2f((unsigned short)(raw >> 16));
  f.z = bf2f((unsigned short)(raw >> 32));
  f.w = bf2f((unsigned short)(raw >> 48));
  return f;
}
__device__ inline void stbf4(unsigned short* p, float4 v) {
  ull raw = (ull)f2bf(v.x) | ((ull)f2bf(v.y) << 16)
          | ((ull)f2bf(v.z) << 32) | ((ull)f2bf(v.w) << 48);
  *(ull*)p = raw;
}
__device__ inline ull pk4_bf16(float v0, float v1, float v2, float v3) {
  return (ull)f2bf(v0) | ((ull)f2bf(v1) << 16) | ((ull)f2bf(v2) << 32) | ((ull)f2bf(v3) << 48);
}

// ---------- fp8 e4m3 helpers ----------
__device__ inline unsigned char f2e4m3(float v) {
#if __has_builtin(__builtin_amdgcn_cvt_pk_fp8_f32)
  return (unsigned char)(__builtin_amdgcn_cvt_pk_fp8_f32(v, v, 0, false) & 0xff);
#else
  union { float f; unsigned int u; } c; c.f = v;
  unsigned char s = (unsigned char)((c.u >> 24) & 0x80);
  float a = fabsf(v);
  if (!(a < 448.f)) return (unsigned char)(s | 0x7e);
  if (a < 0.0009765625f) return s;
  int e = (int)((c.u >> 23) & 0xff) - 127;
  if (e < -6) {
    int q = (int)rintf(ldexpf(a, 9));
    if (q >= 8) return (unsigned char)(s | 0x08);
    return (unsigned char)(s | q);
  }
  int q = (int)rintf(ldexpf(a, 3 - e));
  if (q == 16) { e++; q = 8; }
  if (e > 8) return (unsigned char)(s | 0x7e);
  return (unsigned char)(s | ((e + 7) << 3) | (q - 8));
#endif
}
__device__ inline unsigned int pk4_e4m3(float v0, float v1, float v2, float v3) {
#if __has_builtin(__builtin_amdgcn_cvt_pk_fp8_f32)
  int w = __builtin_amdgcn_cvt_pk_fp8_f32(v0, v1, 0, false);
  w = __builtin_amdgcn_cvt_pk_fp8_f32(v2, v3, w, true);
  return (unsigned int)w;
#else
  return (unsigned int)f2e4m3(v0) | ((unsigned int)f2e4m3(v1) << 8)
       | ((unsigned int)f2e4m3(v2) << 16) | ((unsigned int)f2e4m3(v3) << 24);
#endif
}
template<bool HI>
__device__ inline f32x2 e4m3pk(unsigned int w) {
#if __has_builtin(__builtin_amdgcn_cvt_pk_f32_fp8)
  return __builtin_amdgcn_cvt_pk_f32_fp8((int)w, HI);
#else
  unsigned int h = HI ? (w >> 16) : w;
  f32x2 r;
  #pragma unroll
  for (int j = 0; j < 2; ++j) {
    unsigned char b = (unsigned char)(h >> (8 * j));
    int e = (b >> 3) & 0xf, mm = b & 7;
    float val = e ? ldexpf((float)(8 + mm), e - 10) : ldexpf((float)mm, -9);
    r[j] = (b & 0x80) ? -val : val;
  }
  return r;
#endif
}

// ---------- fp32 -> bf16 bulk convert ----------
__global__ void xconv_k(const float* __restrict__ x, unsigned short* __restrict__ xb, int n8) {
  int i = blockIdx.x * 256 + threadIdx.x;
  if (i >= n8) return;
  const float* p = x + (size_t)i * 8;
  float4 a = *(const float4*)p;
  float4 b = *(const float4*)(p + 4);
  ull lo = (ull)f2bf(a.x) | ((ull)f2bf(a.y) << 16) | ((ull)f2bf(a.z) << 32) | ((ull)f2bf(a.w) << 48);
  ull hi = (ull)f2bf(b.x) | ((ull)f2bf(b.y) << 16) | ((ull)f2bf(b.z) << 32) | ((ull)f2bf(b.w) << 48);
  ull* d = (ull*)(xb + (size_t)i * 8);
  d[0] = lo; d[1] = hi;
}

// ---------- weight transpose + bf16: Wt[n][k] = bf16(W[k][n]) ----------
__global__ void wconv_k(const float* __restrict__ W, unsigned short* __restrict__ Wt,
                        int K, int Ncol) {
  int idx = blockIdx.x * 256 + threadIdx.x;
  if (idx < K * Ncol) {
    int n = idx / K;
    int k = idx - n * K;
    Wt[idx] = f2bf(W[(size_t)k * Ncol + n]);
  }
}

// ---------- Wqkv transpose + bf16 + column permutation ----------
__global__ void wconvqkv_k(const float* __restrict__ W, unsigned short* __restrict__ Wt) {
  int idx = blockIdx.x * 256 + threadIdx.x;   // over 768*256
  if (idx >= 768 * 256) return;
  int j = idx >> 8;          // out col 0..767
  int k = idx & 255;
  int seg = j >> 8;
  int jj = j & 255;
  int h = jj >> 5, t = jj & 31;
  int orig = h * 96 + seg * 32 + t;
  Wt[(size_t)j * 256 + k] = f2bf(W[(size_t)k * 768 + orig]);
}

// ---------- fused-FFN weight build ----------
__global__ void wf1_k(const float* __restrict__ W1, unsigned short* __restrict__ wf) {
  int idx = blockIdx.x * 256 + threadIdx.x;   // over 256*256
  if (idx >= 256 * 256) return;
  int n = idx >> 8, k = idx & 255;
  wf[(size_t)n * 512 + k] = f2bf(W1[(size_t)k * 256 + n]);
}
__global__ void wfc_k(const float* __restrict__ Wout, const float* __restrict__ W1,
                      unsigned short* __restrict__ wf) {
  int idx = blockIdx.x * 256 + threadIdx.x;   // over 256*256
  if (idx >= 256 * 256) return;
  int a = idx >> 8, n = idx & 255;            // a block-uniform, n coalesced
  float s = 0.f;
  #pragma unroll 4
  for (int j = 0; j < 256; ++j)
    s += Wout[(size_t)a * 256 + j] * W1[(size_t)(256 + j) * 256 + n];
  wf[(size_t)n * 512 + 256 + a] = f2bf(s);
}
__global__ void bfc_k(const float* __restrict__ bout, const float* __restrict__ b1,
                      const float* __restrict__ W1, float* __restrict__ bc) {
  int n = threadIdx.x;
  float s = b1[n];
  for (int j = 0; j < 256; ++j)
    s += bout[j] * W1[(size_t)(256 + j) * 256 + n];
  bc[n] = s;
}

// ---------- CSR build ----------
__global__ void hist_k(const int* __restrict__ dst, int* __restrict__ deg, int E) {
  int e = blockIdx.x * 256 + threadIdx.x;
  if (e < E) atomicAdd(&deg[dst[e]], 1);
}

__global__ __launch_bounds__(SCB) void bsum_k(const int* __restrict__ deg, int* __restrict__ bsum, int n) {
  int tid = threadIdx.x;
  int i = blockIdx.x * SCB + tid;
  int v = (i < n) ? deg[i] : 0;
  #pragma unroll
  for (int d = 1; d < 64; d <<= 1) v += __shfl_xor(v, d);
  __shared__ int wsum[8];
  if ((tid & 63) == 0) wsum[tid >> 6] = v;
  __syncthreads();
  if (tid == 0) {
    int s = 0;
    #pragma unroll
    for (int j = 0; j < 8; ++j) s += wsum[j];
    bsum[blockIdx.x] = s;
  }
}

__global__ __launch_bounds__(128) void bscan_k(int* __restrict__ bsum, int nb) {
  __shared__ int tmp[128];
  int tid = threadIdx.x;
  int v = (tid < nb) ? bsum[tid] : 0;
  tmp[tid] = v;
  __syncthreads();
  for (int d = 1; d < 128; d <<= 1) {
    int t = (tid >= d) ? tmp[tid - d] : 0;
    __syncthreads();
    tmp[tid] += t;
    __syncthreads();
  }
  if (tid < nb) bsum[tid] = tmp[tid];
}

__global__ __launch_bounds__(SCB) void offs_k(const int* __restrict__ deg, const int* __restrict__ bsum,
                                              int* __restrict__ offs, int n) {
  int tid = threadIdx.x, lane = tid & 63, wid = tid >> 6;
  int b = blockIdx.x;
  int i = b * SCB + tid;
  int v = (i < n) ? deg[i] : 0;
  int incl = v;
  #pragma unroll
  for (int d = 1; d < 64; d <<= 1) { int t = __shfl_up(incl, d); if (lane >= d) incl += t; }
  __shared__ int wsum[8];
  if (lane == 63) wsum[wid] = incl;
  __syncthreads();
  if (tid < 8) {
    int s = wsum[tid];
    #pragma unroll
    for (int d = 1; d < 8; d <<= 1) { int t = __shfl_up(s, d); if (tid >= d) s += t; }
    wsum[tid] = s;
  }
  __syncthreads();
  int base = (b > 0 ? bsum[b - 1] : 0) + (wid > 0 ? wsum[wid - 1] : 0);
  if (i < n) offs[i] = base + incl - v;
  if (i == n - 1) offs[n] = base + incl;
}

__global__ void scatter_k(const int* __restrict__ src, const int* __restrict__ dst,
                          int* __restrict__ cursor, int* __restrict__ ssrc, int E) {
  int e = blockIdx.x * 256 + threadIdx.x;
  if (e < E) {
    int p = atomicAdd(&cursor[dst[e]], 1);
    ssrc[p] = src[e];
  }
}

// ---------- per-node softmax attention, fp8 K/V, fixed-shift ----------
__global__ __launch_bounds__(256) void attn_k(
    const unsigned short* Q,
    const unsigned char* __restrict__ K8,
    const unsigned char* __restrict__ V8,
    const int* __restrict__ offs,
    const int* __restrict__ ssrc,
    unsigned short* agg, int N)
{
  int n = blockIdx.x * 4 + (threadIdx.x >> 6);
  if (n >= N) return;
  int lane = threadIdx.x & 63;
  int col = lane << 2;
  const float scale = 0.17677669529663689f;
  float4 q4 = ldbf4(Q + (size_t)n * NDIM + col);
  q4.x *= scale; q4.y *= scale; q4.z *= scale; q4.w *= scale;
  int e0 = offs[n], e1 = offs[n + 1];
  float den = 0.f;
  float ax = 0.f, ay = 0.f, az = 0.f, aw = 0.f;
  int e = e0;
  for (; e + 8 <= e1; e += 8) {
    unsigned int kw[8], vw[8];
    #pragma unroll
    for (int j = 0; j < 8; ++j) {
      int s = ssrc[e + j];
      kw[j] = *(const unsigned int*)(K8 + (size_t)s * NDIM + col);
      vw[j] = *(const unsigned int*)(V8 + (size_t)s * NDIM + col);
    }
    float d[8];
    #pragma unroll
    for (int j = 0; j < 8; ++j) {
      f32x2 k01 = e4m3pk<false>(kw[j]);
      f32x2 k23 = e4m3pk<true>(kw[j]);
      d[j] = q4.x * k01[0] + q4.y * k01[1] + q4.z * k23[0] + q4.w * k23[1];
    }
    #pragma unroll
    for (int j = 0; j < 8; ++j) {
      d[j] += __shfl_xor(d[j], 1);
      d[j] += __shfl_xor(d[j], 2);
      d[j] += __shfl_xor(d[j], 4);
    }
    #pragma unroll
    for (int j = 0; j < 8; ++j) {
      float p = __expf(d[j]);
      den += p;
      f32x2 v01 = e4m3pk<false>(vw[j]);
      f32x2 v23 = e4m3pk<true>(vw[j]);
      ax += p * v01[0]; ay += p * v01[1];
      az += p * v23[0]; aw += p * v23[1];
    }
  }
  for (; e + 4 <= e1; e += 4) {
    unsigned int kw[4], vw[4];
    #pragma unroll
    for (int j = 0; j < 4; ++j) {
      int s = ssrc[e + j];
      kw[j] = *(const unsigned int*)(K8 + (size_t)s * NDIM + col);
      vw[j] = *(const unsigned int*)(V8 + (size_t)s * NDIM + col);
    }
    float d[4];
    #pragma unroll
    for (int j = 0; j < 4; ++j) {
      f32x2 k01 = e4m3pk<false>(kw[j]);
      f32x2 k23 = e4m3pk<true>(kw[j]);
      d[j] = q4.x * k01[0] + q4.y * k01[1] + q4.z * k23[0] + q4.w * k23[1];
    }
    #pragma unroll
    for (int j = 0; j < 4; ++j) {
      d[j] += __shfl_xor(d[j], 1);
      d[j] += __shfl_xor(d[j], 2);
      d[j] += __shfl_xor(d[j], 4);
    }
    #pragma unroll
    for (int j = 0; j < 4; ++j) {
      float p = __expf(d[j]);
      den += p;
      f32x2 v01 = e4m3pk<false>(vw[j]);
      f32x2 v23 = e4m3pk<true>(vw[j]);
      ax += p * v01[0]; ay += p * v01[1];
      az += p * v23[0]; aw += p * v23[1];
    }
  }
  for (; e < e1; ++e) {
    int s = ssrc[e];
    unsigned int kw = *(const unsigned int*)(K8 + (size_t)s * NDIM + col);
    unsigned int vw = *(const unsigned int*)(V8 + (size_t)s * NDIM + col);
    f32x2 k01 = e4m3pk<false>(kw);
    f32x2 k23 = e4m3pk<true>(kw);
    float d = q4.x * k01[0] + q4.y * k01[1] + q4.z * k23[0] + q4.w * k23[1];
    d += __shfl_xor(d, 1);
    d += __shfl_xor(d, 2);
    d += __shfl_xor(d, 4);
    float p = __expf(d);
    den += p;
    f32x2 v01 = e4m3pk<false>(vw);
    f32x2 v23 = e4m3pk<true>(vw);
    ax += p * v01[0]; ay += p * v01[1];
    az += p * v23[0]; aw += p * v23[1];
  }
  float inv = (den > 0.f) ? 1.f / den : 0.f;
  stbf4(agg + (size_t)n * NDIM + col, make_float4(ax * inv, ay * inv, az * inv, aw * inv));
}

// ---------- MFMA GEMM: swizzled LDS, XCD swizzle, operand-swapped MFMA,
// ---------- coalesced epilogue via per-wave LDS transpose (8KB slab each) ----------
// EPI: 0 = fp32, 2 = gelu + bf16, 3 = qkv split (cols pre-permuted: Q bf16 | K fp8 | V fp8)
template<int EPI>
__global__ __launch_bounds__(256, 4) void mgemm_k(
    const unsigned short* __restrict__ A1, const unsigned short* __restrict__ A2,
    const unsigned short* __restrict__ Wt, const float* __restrict__ bias,
    float* __restrict__ Cf, unsigned short* __restrict__ Cb,
    unsigned short* __restrict__ Oq, unsigned char* __restrict__ Ok, unsigned char* __restrict__ Ov,
    int M, int K1, int K, int Ncol, int ldb, int nct)
{
  __shared__ char smem[32768];
  unsigned short* As = (unsigned short*)smem;
  unsigned short* Bs = (unsigned short*)(smem + 16384);
  const int tid = threadIdx.x;
  const int lane = tid & 63;
  const int wid = tid >> 6;

  // XCD-aware bijective block swizzle (m204)
  const int nwg = gridDim.x;
  const int q8 = nwg >> 3, r8 = nwg & 7;
  const int xcd = blockIdx.x & 7, idx8 = blockIdx.x >> 3;
  const int swz = (xcd < r8 ? xcd * (q8 + 1) : r8 * (q8 + 1) + (xcd - r8) * q8) + idx8;
  const int bmt = swz / nct;
  const int bnt = swz - bmt * nct;
  const int bm = bmt * 128;
  const int bn = bnt * 128;

  const int wr = (wid >> 1) << 6;
  const int wc = (wid & 1) << 6;
  const int l15 = lane & 15, lhi = lane >> 4;
  const int srow = lane >> 3;
  const int ssl = (((lane & 7) ^ (lane >> 3)) << 3);

  f32x4 acc[4][4];
  #pragma unroll
  for (int i = 0; i < 4; ++i)
    #pragma unroll
    for (int j = 0; j < 4; ++j) acc[i][j] = (f32x4){0.f, 0.f, 0.f, 0.f};

  for (int k0 = 0; k0 < K; k0 += 64) {
    const unsigned short* Ab;
    int ks;
    if (k0 < K1) { Ab = A1; ks = k0; } else { Ab = A2; ks = k0 - K1; }
    #pragma unroll
    for (int t = 0; t < 4; ++t) {
      int qi = wid * 4 + t;
      const unsigned short* ga = Ab + (size_t)(bm + qi * 8 + srow) * 256 + ks + ssl;
      __builtin_amdgcn_global_load_lds(
          (const __attribute__((address_space(1))) void*)ga,
          (__attribute__((address_space(3))) void*)&As[qi * 512], 16, 0, 0);
      const unsigned short* gb = Wt + (size_t)(bn + qi * 8 + srow) * ldb + k0 + ssl;
      __builtin_amdgcn_global_load_lds(
          (const __attribute__((address_space(1))) void*)gb,
          (__attribute__((address_space(3))) void*)&Bs[qi * 512], 16, 0, 0);
    }
    __syncthreads();
    #pragma unroll
    for (int kk = 0; kk < 64; kk += 32) {
      bf16x8 af[4], bfr[4];
      #pragma unroll
      for (int mi = 0; mi < 4; ++mi) {
        int rA = wr + mi * 16 + l15;
        af[mi] = *(const bf16x8*)&As[rA * 64 + ((((kk >> 3) + lhi) ^ (rA & 7)) << 3)];
      }
      #pragma unroll
      for (int ni = 0; ni < 4; ++ni) {
        int rB = wc + ni * 16 + l15;
        bfr[ni] = *(const bf16x8*)&Bs[rB * 64 + ((((kk >> 3) + lhi) ^ (rB & 7)) << 3)];
      }
      #pragma unroll
      for (int mi = 0; mi < 4; ++mi)
        #pragma unroll
        for (int ni = 0; ni < 4; ++ni)
          acc[mi][ni] = __builtin_amdgcn_mfma_f32_16x16x32_bf16(bfr[ni], af[mi], acc[mi][ni], 0, 0, 0);
    }
    __syncthreads();
  }
  // staging LDS now dead; each wave uses a private 8KB slab for store transpose.
  // lane holds C[bm+wr+mi*16+l15][bn+wc+ni*16+lhi*4 + i], i=0..3

  if (EPI == 0) {
    float* slabf = (float*)(smem + wid * 8192);   // 64 x 32 fp32
    #pragma unroll
    for (int half = 0; half < 2; ++half) {
      #pragma unroll
      for (int nj = 0; nj < 2; ++nj) {
        int ni = half * 2 + nj;
        int cl = nj * 16 + (lhi << 2);
        float4 bb = *(const float4*)&bias[bn + wc + half * 32 + cl];
        #pragma unroll
        for (int mi = 0; mi < 4; ++mi) {
          int rl = mi * 16 + l15;
          *(float4*)&slabf[rl * 32 + cl] = make_float4(
              acc[mi][ni][0] + bb.x, acc[mi][ni][1] + bb.y,
              acc[mi][ni][2] + bb.z, acc[mi][ni][3] + bb.w);
        }
      }
      asm volatile("s_waitcnt lgkmcnt(0)" ::: "memory");
      __builtin_amdgcn_sched_barrier(0);
      int rl0 = lane >> 3, coff = (lane & 7) << 2;
      #pragma unroll
      for (int t = 0; t < 8; ++t) {
        int rl = t * 8 + rl0;
        int gr = bm + wr + rl;
        if (gr < M)
          *(float4*)&Cf[(size_t)gr * Ncol + bn + wc + half * 32 + coff] =
              *(float4*)&slabf[rl * 32 + coff];
      }
      if (half == 0) {
        asm volatile("s_waitcnt lgkmcnt(0)" ::: "memory");
        __builtin_amdgcn_sched_barrier(0);
      }
    }
  } else if (EPI == 2) {
    unsigned short* slab = (unsigned short*)(smem + wid * 8192);   // 64 x 64 bf16
    #pragma unroll
    for (int ni = 0; ni < 4; ++ni) {
      int cl = ni * 16 + (lhi << 2);
      float4 bb = *(const float4*)&bias[bn + wc + cl];
      #pragma unroll
      for (int mi = 0; mi < 4; ++mi) {
        int rl = mi * 16 + l15;
        float v0 = acc[mi][ni][0] + bb.x;
        float v1 = acc[mi][ni][1] + bb.y;
        float v2 = acc[mi][ni][2] + bb.z;
        float v3 = acc[mi][ni][3] + bb.w;
        v0 = 0.5f * v0 * (1.0f + erff(v0 * 0.70710678118654752f));
        v1 = 0.5f * v1 * (1.0f + erff(v1 * 0.70710678118654752f));
        v2 = 0.5f * v2 * (1.0f + erff(v2 * 0.70710678118654752f));
        v3 = 0.5f * v3 * (1.0f + erff(v3 * 0.70710678118654752f));
        *(ull*)&slab[rl * 64 + cl] = pk4_bf16(v0, v1, v2, v3);
      }
    }
    asm volatile("s_waitcnt lgkmcnt(0)" ::: "memory");
    __builtin_amdgcn_sched_barrier(0);
    int rl0 = lane >> 3, coff = (lane & 7) << 3;
    #pragma unroll
    for (int t = 0; t < 8; ++t) {
      int rl = t * 8 + rl0;
      int gr = bm + wr + rl;
      if (gr < M)
        *(float4*)&Cb[(size_t)gr * Ncol + bn + wc + coff] = *(float4*)&slab[rl * 64 + coff];
    }
  } else {
    // EPI 3: seg uniform per 128-tile (tiles 0-1 Q bf16, 2-3 K fp8, 4-5 V fp8)
    const int seg = (bn + wc) >> 8;
    const int jjbase = (bn + wc) & 255;
    if (seg == 0) {
      unsigned short* slab = (unsigned short*)(smem + wid * 8192);
      #pragma unroll
      for (int ni = 0; ni < 4; ++ni) {
        int cl = ni * 16 + (lhi << 2);
        int jj = jjbase + cl;
        float4 bb = *(const float4*)&bias[(jj >> 5) * 96 + (jj & 31)];
        #pragma unroll
        for (int mi = 0; mi < 4; ++mi) {
          int rl = mi * 16 + l15;
          *(ull*)&slab[rl * 64 + cl] = pk4_bf16(
              acc[mi][ni][0] + bb.x, acc[mi][ni][1] + bb.y,
              acc[mi][ni][2] + bb.z, acc[mi][ni][3] + bb.w);
        }
      }
      asm volatile("s_waitcnt lgkmcnt(0)" ::: "memory");
      __builtin_amdgcn_sched_barrier(0);
      int rl0 = lane >> 3, coff = (lane & 7) << 3;
      #pragma unroll
      for (int t = 0; t < 8; ++t) {
        int rl = t * 8 + rl0;
        int gr = bm + wr + rl;
        if (gr < M)
          *(float4*)&Oq[(size_t)gr * NDIM + jjbase + coff] = *(float4*)&slab[rl * 64 + coff];
      }
    } else {
      unsigned char* slab8 = (unsigned char*)(smem + wid * 8192);   // 64 x 64 fp8
      unsigned char* dstp = (seg == 1) ? Ok : Ov;
      #pragma unroll
      for (int ni = 0; ni < 4; ++ni) {
        int cl = ni * 16 + (lhi << 2);
        int jj = jjbase + cl;
        float4 bb = *(const float4*)&bias[(jj >> 5) * 96 + seg * 32 + (jj & 31)];
        #pragma unroll
        for (int mi = 0; mi < 4; ++mi) {
          int rl = mi * 16 + l15;
          *(unsigned int*)&slab8[rl * 64 + cl] = pk4_e4m3(
              acc[mi][ni][0] + bb.x, acc[mi][ni][1] + bb.y,
              acc[mi][ni][2] + bb.z, acc[mi][ni][3] + bb.w);
        }
      }
      asm volatile("s_waitcnt lgkmcnt(0)" ::: "memory");
      __builtin_amdgcn_sched_barrier(0);
      int rl0 = lane >> 2, coff = (lane & 3) << 4;
      #pragma unroll
      for (int t = 0; t < 4; ++t) {
        int rl = t * 16 + rl0;
        int gr = bm + wr + rl;
        if (gr < M)
          *(float4*)&dstp[(size_t)gr * NDIM + jjbase + coff] = *(float4*)&slab8[rl * 64 + coff];
      }
    }
  }
}

extern "C" void kernel_launch(void* const* d_in, const int* in_sizes, int n_in,
                              void* d_out, int out_size, void* d_ws, size_t ws_size,
                              hipStream_t stream) {
  (void)n_in; (void)out_size; (void)ws_size;
  const float* x    = (const float*)d_in[0];
  const int*   src  = (const int*)d_in[1];
  const int*   dst  = (const int*)d_in[2];
  const float* Wqkv = (const float*)d_in[3];
  const float* bqkv = (const float*)d_in[4];
  const float* Wout = (const float*)d_in[5];
  const float* bout = (const float*)d_in[6];
  const float* W1   = (const float*)d_in[7];
  const float* b1   = (const float*)d_in[8];
  const float* W2   = (const float*)d_in[9];
  const float* b2   = (const float*)d_in[10];
  float* out = (float*)d_out;

  const int N = in_sizes[0] / NDIM;   // 50000
  const int E = in_sizes[1];          // 800000
  const int Mp = (N + 127) & ~127;    // 50048
  const int nb = (N + SCB - 1) / SCB;

  char* ws = (char*)d_ws;
  size_t off = 0;
  auto alloc = [&](size_t bytes) -> char* {
    char* p = ws + off;
    off += (bytes + 255) & ~(size_t)255;
    return p;
  };
  unsigned short* xb   = (unsigned short*)alloc((size_t)Mp * NDIM * 2);
  unsigned short* Q    = (unsigned short*)alloc((size_t)Mp * NDIM * 2);
  unsigned short* Kb   = (unsigned short*)alloc((size_t)Mp * NDIM * 2);
  unsigned short* Vb   = (unsigned short*)alloc((size_t)Mp * NDIM * 2);
  unsigned short* wqkvt = (unsigned short*)alloc((size_t)768 * 256 * 2);
  unsigned short* wft   = (unsigned short*)alloc((size_t)256 * 512 * 2);
  unsigned short* w2t   = (unsigned short*)alloc((size_t)256 * 256 * 2);
  float*          bc    = (float*)alloc(256 * 4);
  int* deg    = (int*)alloc((size_t)N * 4);
  int* offs   = (int*)alloc((size_t)(N + 1) * 4);
  int* cursor = (int*)alloc((size_t)N * 4);
  int* ssrc   = (int*)alloc((size_t)E * 4);
  int* bsum   = (int*)alloc((size_t)nb * 4);

  unsigned char* K8 = (unsigned char*)Kb;
  unsigned char* V8 = (unsigned char*)Vb;
  unsigned short* agg = Q;    // attn writes in place over Q
  unsigned short* h1  = Kb;   // Kb dead after attn

  // input/weight prep
  xconv_k<<<(N * NDIM / 8 + 255) / 256, 256, 0, stream>>>(x, xb, N * NDIM / 8);
  wconvqkv_k<<<(768 * 256 + 255) / 256, 256, 0, stream>>>(Wqkv, wqkvt);
  wf1_k<<<256, 256, 0, stream>>>(W1, wft);
  wfc_k<<<256, 256, 0, stream>>>(Wout, W1, wft);
  bfc_k<<<1, 256, 0, stream>>>(bout, b1, W1, bc);
  wconv_k<<<(256 * 256 + 255) / 256, 256, 0, stream>>>(W2, w2t, 256, 256);

  // CSR build
  hipMemsetAsync(deg, 0, (size_t)N * 4, stream);
  hist_k<<<(E + 255) / 256, 256, 0, stream>>>(dst, deg, E);
  bsum_k<<<nb, SCB, 0, stream>>>(deg, bsum, N);
  bscan_k<<<1, 128, 0, stream>>>(bsum, nb);
  offs_k<<<nb, SCB, 0, stream>>>(deg, bsum, offs, N);
  hipMemcpyAsync(cursor, offs, (size_t)N * 4, hipMemcpyDeviceToDevice, stream);
  scatter_k<<<(E + 255) / 256, 256, 0, stream>>>(src, dst, cursor, ssrc, E);

  const int mt = Mp / 128;   // 391

  // QKV projection -> Q (bf16), K8/V8 (fp8); wqkvt column-permuted
  mgemm_k<3><<<mt * 6, 256, 0, stream>>>(
      xb, nullptr, wqkvt, bqkv, nullptr, nullptr, Q, K8, V8, N, 256, 256, 768, 256, 6);

  // edge-softmax aggregation (agg == Q in place)
  attn_k<<<(N + 3) / 4, 256, 0, stream>>>(Q, K8, V8, offs, ssrc, agg, N);

  // FUSED FFN-in: gelu(x@W1a + agg@(Wout@W1b) + bc) -> h1 (bf16)
  mgemm_k<2><<<mt * 2, 256, 0, stream>>>(
      xb, agg, wft, bc, nullptr, h1, nullptr, nullptr, nullptr, N, 256, 512, 256, 512, 2);

  // h1 @ W2 + b2 -> out (fp32)
  mgemm_k<0><<<mt * 2, 256, 0, stream>>>(
      h1, nullptr, w2t, b2, out, nullptr, nullptr, nullptr, nullptr, N, 256, 256, 256, 256, 2);
}

// Round 10
// 265.810 us; speedup vs baseline: 1.1552x; 1.1124x over previous
//
#include <hip/hip_runtime.h>
#include <hip/hip_bf16.h>
#include <math.h>

#define NDIM 256
#define HDIM 32
#define SCB 512

typedef __attribute__((ext_vector_type(8))) short bf16x8;
typedef __attribute__((ext_vector_type(4))) float f32x4;
typedef __attribute__((ext_vector_type(2))) float f32x2;
typedef unsigned long long ull;

// ---------- bf16 helpers ----------
__device__ inline float bf2f(unsigned short u) {
  union { unsigned int i; float f; } c; c.i = ((unsigned int)u) << 16; return c.f;
}
__device__ inline unsigned short f2bf(float f) {
  union { float f; unsigned int i; } c; c.f = f;
  unsigned int x = c.i;
  unsigned int lsb = (x >> 16) & 1u;
  x += 0x7fffu + lsb;
  return (unsigned short)(x >> 16);
}
__device__ inline float4 ldbf4(const unsigned short* p) {
  ull raw = *(const ull*)p;
  float4 f;
  f.x = bf2f((unsigned short)(raw));
  f.y = bf2f((unsigned short)(raw >> 16));
  f.z = bf2f((unsigned short)(raw >> 32));
  f.w = bf2f((unsigned short)(raw >> 48));
  return f;
}
__device__ inline void stbf4(unsigned short* p, float4 v) {
  ull raw = (ull)f2bf(v.x) | ((ull)f2bf(v.y) << 16)
          | ((ull)f2bf(v.z) << 32) | ((ull)f2bf(v.w) << 48);
  *(ull*)p = raw;
}
__device__ inline ull pk4_bf16(float v0, float v1, float v2, float v3) {
  return (ull)f2bf(v0) | ((ull)f2bf(v1) << 16) | ((ull)f2bf(v2) << 32) | ((ull)f2bf(v3) << 48);
}

// ---------- fp8 e4m3 helpers ----------
__device__ inline unsigned char f2e4m3(float v) {
#if __has_builtin(__builtin_amdgcn_cvt_pk_fp8_f32)
  return (unsigned char)(__builtin_amdgcn_cvt_pk_fp8_f32(v, v, 0, false) & 0xff);
#else
  union { float f; unsigned int u; } c; c.f = v;
  unsigned char s = (unsigned char)((c.u >> 24) & 0x80);
  float a = fabsf(v);
  if (!(a < 448.f)) return (unsigned char)(s | 0x7e);
  if (a < 0.0009765625f) return s;
  int e = (int)((c.u >> 23) & 0xff) - 127;
  if (e < -6) {
    int q = (int)rintf(ldexpf(a, 9));
    if (q >= 8) return (unsigned char)(s | 0x08);
    return (unsigned char)(s | q);
  }
  int q = (int)rintf(ldexpf(a, 3 - e));
  if (q == 16) { e++; q = 8; }
  if (e > 8) return (unsigned char)(s | 0x7e);
  return (unsigned char)(s | ((e + 7) << 3) | (q - 8));
#endif
}
__device__ inline unsigned int pk4_e4m3(float v0, float v1, float v2, float v3) {
#if __has_builtin(__builtin_amdgcn_cvt_pk_fp8_f32)
  int w = __builtin_amdgcn_cvt_pk_fp8_f32(v0, v1, 0, false);
  w = __builtin_amdgcn_cvt_pk_fp8_f32(v2, v3, w, true);
  return (unsigned int)w;
#else
  return (unsigned int)f2e4m3(v0) | ((unsigned int)f2e4m3(v1) << 8)
       | ((unsigned int)f2e4m3(v2) << 16) | ((unsigned int)f2e4m3(v3) << 24);
#endif
}
template<bool HI>
__device__ inline f32x2 e4m3pk(unsigned int w) {
#if __has_builtin(__builtin_amdgcn_cvt_pk_f32_fp8)
  return __builtin_amdgcn_cvt_pk_f32_fp8((int)w, HI);
#else
  unsigned int h = HI ? (w >> 16) : w;
  f32x2 r;
  #pragma unroll
  for (int j = 0; j < 2; ++j) {
    unsigned char b = (unsigned char)(h >> (8 * j));
    int e = (b >> 3) & 0xf, mm = b & 7;
    float val = e ? ldexpf((float)(8 + mm), e - 10) : ldexpf((float)mm, -9);
    r[j] = (b & 0x80) ? -val : val;
  }
  return r;
#endif
}

// ---------- FUSED prep: xconv + all weight prep + degree histogram ----------
// grid partition: [0,nbx) xconv | [nbx,nbx+nbw) weight prep | rest hist
__global__ void fuse0_k(
    const float* __restrict__ x, unsigned short* __restrict__ xb, int n8, int nbx,
    const float* __restrict__ Wqkv, unsigned short* __restrict__ wqkvt,
    const float* __restrict__ W1, unsigned short* __restrict__ wf,
    const float* __restrict__ W2, unsigned short* __restrict__ w2t,
    const float* __restrict__ Wout, const float* __restrict__ bout,
    const float* __restrict__ b1, float* __restrict__ bc, int nbw,
    const int* __restrict__ dst, int* __restrict__ deg, int E)
{
  int b = blockIdx.x;
  int tid = threadIdx.x;
  if (b < nbx) {
    int i = b * 256 + tid;
    if (i < n8) {
      const float* p = x + (size_t)i * 8;
      float4 a = *(const float4*)p;
      float4 bv = *(const float4*)(p + 4);
      ull lo = (ull)f2bf(a.x) | ((ull)f2bf(a.y) << 16) | ((ull)f2bf(a.z) << 32) | ((ull)f2bf(a.w) << 48);
      ull hi = (ull)f2bf(bv.x) | ((ull)f2bf(bv.y) << 16) | ((ull)f2bf(bv.z) << 32) | ((ull)f2bf(bv.w) << 48);
      ull* d = (ull*)(xb + (size_t)i * 8);
      d[0] = lo; d[1] = hi;
    }
    return;
  }
  b -= nbx;
  if (b < nbw) {
    int idx = b * 256 + tid;
    if (idx < 196608) {
      // Wqkv transpose + bf16 + column permutation
      int j = idx >> 8, k = idx & 255;
      int seg = j >> 8, jj = j & 255;
      int h = jj >> 5, t = jj & 31;
      int orig = h * 96 + seg * 32 + t;
      wqkvt[(size_t)j * 256 + k] = f2bf(Wqkv[(size_t)k * 768 + orig]);
    } else if (idx < 262144) {
      int i2 = idx - 196608;
      int n = i2 >> 8, k = i2 & 255;
      wf[(size_t)n * 512 + k] = f2bf(W1[(size_t)k * 256 + n]);
    } else if (idx < 327680) {
      int i3 = idx - 262144;
      int n = i3 >> 8, k = i3 & 255;
      w2t[(size_t)n * 256 + k] = f2bf(W2[(size_t)k * 256 + n]);
    } else if (idx < 393216) {
      int i4 = idx - 327680;
      int a = i4 >> 8, n = i4 & 255;
      float s = 0.f;
      #pragma unroll 4
      for (int j = 0; j < 256; ++j)
        s += Wout[(size_t)a * 256 + j] * W1[(size_t)(256 + j) * 256 + n];
      wf[(size_t)n * 512 + 256 + a] = f2bf(s);
    } else if (idx < 393472) {
      int n = idx - 393216;
      float s = b1[n];
      for (int j = 0; j < 256; ++j)
        s += bout[j] * W1[(size_t)(256 + j) * 256 + n];
      bc[n] = s;
    }
    return;
  }
  b -= nbw;
  int e = b * 256 + tid;
  if (e < E) atomicAdd(&deg[dst[e]], 1);
}

// ---------- CSR scan ----------
__global__ __launch_bounds__(SCB) void bsum_k(const int* __restrict__ deg, int* __restrict__ bsum, int n) {
  int tid = threadIdx.x;
  int i = blockIdx.x * SCB + tid;
  int v = (i < n) ? deg[i] : 0;
  #pragma unroll
  for (int d = 1; d < 64; d <<= 1) v += __shfl_xor(v, d);
  __shared__ int wsum[8];
  if ((tid & 63) == 0) wsum[tid >> 6] = v;
  __syncthreads();
  if (tid == 0) {
    int s = 0;
    #pragma unroll
    for (int j = 0; j < 8; ++j) s += wsum[j];
    bsum[blockIdx.x] = s;
  }
}

__global__ __launch_bounds__(128) void bscan_k(int* __restrict__ bsum, int nb) {
  __shared__ int tmp[128];
  int tid = threadIdx.x;
  int v = (tid < nb) ? bsum[tid] : 0;
  tmp[tid] = v;
  __syncthreads();
  for (int d = 1; d < 128; d <<= 1) {
    int t = (tid >= d) ? tmp[tid - d] : 0;
    __syncthreads();
    tmp[tid] += t;
    __syncthreads();
  }
  if (tid < nb) bsum[tid] = tmp[tid];
}

__global__ __launch_bounds__(SCB) void offs_k(const int* __restrict__ deg, const int* __restrict__ bsum,
                                              int* __restrict__ offs, int* __restrict__ cursor, int n) {
  int tid = threadIdx.x, lane = tid & 63, wid = tid >> 6;
  int b = blockIdx.x;
  int i = b * SCB + tid;
  int v = (i < n) ? deg[i] : 0;
  int incl = v;
  #pragma unroll
  for (int d = 1; d < 64; d <<= 1) { int t = __shfl_up(incl, d); if (lane >= d) incl += t; }
  __shared__ int wsum[8];
  if (lane == 63) wsum[wid] = incl;
  __syncthreads();
  if (tid < 8) {
    int s = wsum[tid];
    #pragma unroll
    for (int d = 1; d < 8; d <<= 1) { int t = __shfl_up(s, d); if (tid >= d) s += t; }
    wsum[tid] = s;
  }
  __syncthreads();
  int base = (b > 0 ? bsum[b - 1] : 0) + (wid > 0 ? wsum[wid - 1] : 0);
  if (i < n) {
    int val = base + incl - v;
    offs[i] = val;
    cursor[i] = val;
  }
  if (i == n - 1) offs[n] = base + incl;
}

// ---------- per-node softmax attention, fp8 K/V, fixed-shift ----------
__global__ __launch_bounds__(256) void attn_k(
    const unsigned short* Q,
    const unsigned char* __restrict__ K8,
    const unsigned char* __restrict__ V8,
    const int* __restrict__ offs,
    const int* __restrict__ ssrc,
    unsigned short* agg, int N)
{
  int n = blockIdx.x * 4 + (threadIdx.x >> 6);
  if (n >= N) return;
  int lane = threadIdx.x & 63;
  int col = lane << 2;
  const float scale = 0.17677669529663689f;
  float4 q4 = ldbf4(Q + (size_t)n * NDIM + col);
  q4.x *= scale; q4.y *= scale; q4.z *= scale; q4.w *= scale;
  int e0 = offs[n], e1 = offs[n + 1];
  float den = 0.f;
  float ax = 0.f, ay = 0.f, az = 0.f, aw = 0.f;
  int e = e0;
  for (; e + 8 <= e1; e += 8) {
    unsigned int kw[8], vw[8];
    #pragma unroll
    for (int j = 0; j < 8; ++j) {
      int s = ssrc[e + j];
      kw[j] = *(const unsigned int*)(K8 + (size_t)s * NDIM + col);
      vw[j] = *(const unsigned int*)(V8 + (size_t)s * NDIM + col);
    }
    float d[8];
    #pragma unroll
    for (int j = 0; j < 8; ++j) {
      f32x2 k01 = e4m3pk<false>(kw[j]);
      f32x2 k23 = e4m3pk<true>(kw[j]);
      d[j] = q4.x * k01[0] + q4.y * k01[1] + q4.z * k23[0] + q4.w * k23[1];
    }
    #pragma unroll
    for (int j = 0; j < 8; ++j) {
      d[j] += __shfl_xor(d[j], 1);
      d[j] += __shfl_xor(d[j], 2);
      d[j] += __shfl_xor(d[j], 4);
    }
    #pragma unroll
    for (int j = 0; j < 8; ++j) {
      float p = __expf(d[j]);
      den += p;
      f32x2 v01 = e4m3pk<false>(vw[j]);
      f32x2 v23 = e4m3pk<true>(vw[j]);
      ax += p * v01[0]; ay += p * v01[1];
      az += p * v23[0]; aw += p * v23[1];
    }
  }
  for (; e + 4 <= e1; e += 4) {
    unsigned int kw[4], vw[4];
    #pragma unroll
    for (int j = 0; j < 4; ++j) {
      int s = ssrc[e + j];
      kw[j] = *(const unsigned int*)(K8 + (size_t)s * NDIM + col);
      vw[j] = *(const unsigned int*)(V8 + (size_t)s * NDIM + col);
    }
    float d[4];
    #pragma unroll
    for (int j = 0; j < 4; ++j) {
      f32x2 k01 = e4m3pk<false>(kw[j]);
      f32x2 k23 = e4m3pk<true>(kw[j]);
      d[j] = q4.x * k01[0] + q4.y * k01[1] + q4.z * k23[0] + q4.w * k23[1];
    }
    #pragma unroll
    for (int j = 0; j < 4; ++j) {
      d[j] += __shfl_xor(d[j], 1);
      d[j] += __shfl_xor(d[j], 2);
      d[j] += __shfl_xor(d[j], 4);
    }
    #pragma unroll
    for (int j = 0; j < 4; ++j) {
      float p = __expf(d[j]);
      den += p;
      f32x2 v01 = e4m3pk<false>(vw[j]);
      f32x2 v23 = e4m3pk<true>(vw[j]);
      ax += p * v01[0]; ay += p * v01[1];
      az += p * v23[0]; aw += p * v23[1];
    }
  }
  for (; e < e1; ++e) {
    int s = ssrc[e];
    unsigned int kw = *(const unsigned int*)(K8 + (size_t)s * NDIM + col);
    unsigned int vw = *(const unsigned int*)(V8 + (size_t)s * NDIM + col);
    f32x2 k01 = e4m3pk<false>(kw);
    f32x2 k23 = e4m3pk<true>(kw);
    float d = q4.x * k01[0] + q4.y * k01[1] + q4.z * k23[0] + q4.w * k23[1];
    d += __shfl_xor(d, 1);
    d += __shfl_xor(d, 2);
    d += __shfl_xor(d, 4);
    float p = __expf(d);
    den += p;
    f32x2 v01 = e4m3pk<false>(vw);
    f32x2 v23 = e4m3pk<true>(vw);
    ax += p * v01[0]; ay += p * v01[1];
    az += p * v23[0]; aw += p * v23[1];
  }
  float inv = (den > 0.f) ? 1.f / den : 0.f;
  stbf4(agg + (size_t)n * NDIM + col, make_float4(ax * inv, ay * inv, az * inv, aw * inv));
}

// ---------- FUSED scatter + QKV MFMA GEMM ----------
// blocks [0,nsc): CSR scatter; rest: 128x128 GEMM tiles (structure = R9 mgemm EPI3)
__global__ __launch_bounds__(256, 4) void sqkv_k(
    const int* __restrict__ src, const int* __restrict__ dstv,
    int* __restrict__ cursor, int* __restrict__ ssrc, int E, int nsc,
    const unsigned short* __restrict__ A1, const unsigned short* __restrict__ Wt,
    const float* __restrict__ bias,
    unsigned short* __restrict__ Oq, unsigned char* __restrict__ Ok, unsigned char* __restrict__ Ov,
    int M)
{
  __shared__ char smem[32768];
  if (blockIdx.x < nsc) {
    int e = blockIdx.x * 256 + threadIdx.x;
    if (e < E) {
      int p = atomicAdd(&cursor[dstv[e]], 1);
      ssrc[p] = src[e];
    }
    return;
  }
  unsigned short* As = (unsigned short*)smem;
  unsigned short* Bs = (unsigned short*)(smem + 16384);
  const int tid = threadIdx.x;
  const int lane = tid & 63;
  const int wid = tid >> 6;

  const int nwg = gridDim.x - nsc;
  const int bid = blockIdx.x - nsc;
  const int q8 = nwg >> 3, r8 = nwg & 7;
  const int xcd = bid & 7, idx8 = bid >> 3;
  const int swz = (xcd < r8 ? xcd * (q8 + 1) : r8 * (q8 + 1) + (xcd - r8) * q8) + idx8;
  const int nct = 6;
  const int bmt = swz / nct;
  const int bnt = swz - bmt * nct;
  const int bm = bmt * 128;
  const int bn = bnt * 128;

  const int wr = (wid >> 1) << 6;
  const int wc = (wid & 1) << 6;
  const int l15 = lane & 15, lhi = lane >> 4;
  const int srow = lane >> 3;
  const int ssl = (((lane & 7) ^ (lane >> 3)) << 3);

  f32x4 acc[4][4];
  #pragma unroll
  for (int i = 0; i < 4; ++i)
    #pragma unroll
    for (int j = 0; j < 4; ++j) acc[i][j] = (f32x4){0.f, 0.f, 0.f, 0.f};

  for (int k0 = 0; k0 < 256; k0 += 64) {
    #pragma unroll
    for (int t = 0; t < 4; ++t) {
      int qi = wid * 4 + t;
      const unsigned short* ga = A1 + (size_t)(bm + qi * 8 + srow) * 256 + k0 + ssl;
      __builtin_amdgcn_global_load_lds(
          (const __attribute__((address_space(1))) void*)ga,
          (__attribute__((address_space(3))) void*)&As[qi * 512], 16, 0, 0);
      const unsigned short* gb = Wt + (size_t)(bn + qi * 8 + srow) * 256 + k0 + ssl;
      __builtin_amdgcn_global_load_lds(
          (const __attribute__((address_space(1))) void*)gb,
          (__attribute__((address_space(3))) void*)&Bs[qi * 512], 16, 0, 0);
    }
    __syncthreads();
    #pragma unroll
    for (int kk = 0; kk < 64; kk += 32) {
      bf16x8 af[4], bfr[4];
      #pragma unroll
      for (int mi = 0; mi < 4; ++mi) {
        int rA = wr + mi * 16 + l15;
        af[mi] = *(const bf16x8*)&As[rA * 64 + ((((kk >> 3) + lhi) ^ (rA & 7)) << 3)];
      }
      #pragma unroll
      for (int ni = 0; ni < 4; ++ni) {
        int rB = wc + ni * 16 + l15;
        bfr[ni] = *(const bf16x8*)&Bs[rB * 64 + ((((kk >> 3) + lhi) ^ (rB & 7)) << 3)];
      }
      #pragma unroll
      for (int mi = 0; mi < 4; ++mi)
        #pragma unroll
        for (int ni = 0; ni < 4; ++ni)
          acc[mi][ni] = __builtin_amdgcn_mfma_f32_16x16x32_bf16(bfr[ni], af[mi], acc[mi][ni], 0, 0, 0);
    }
    __syncthreads();
  }

  const int seg = (bn + wc) >> 8;
  const int jjbase = (bn + wc) & 255;
  if (seg == 0) {
    unsigned short* slab = (unsigned short*)(smem + wid * 8192);
    #pragma unroll
    for (int ni = 0; ni < 4; ++ni) {
      int cl = ni * 16 + (lhi << 2);
      int jj = jjbase + cl;
      float4 bb = *(const float4*)&bias[(jj >> 5) * 96 + (jj & 31)];
      #pragma unroll
      for (int mi = 0; mi < 4; ++mi) {
        int rl = mi * 16 + l15;
        *(ull*)&slab[rl * 64 + cl] = pk4_bf16(
            acc[mi][ni][0] + bb.x, acc[mi][ni][1] + bb.y,
            acc[mi][ni][2] + bb.z, acc[mi][ni][3] + bb.w);
      }
    }
    asm volatile("s_waitcnt lgkmcnt(0)" ::: "memory");
    __builtin_amdgcn_sched_barrier(0);
    int rl0 = lane >> 3, coff = (lane & 7) << 3;
    #pragma unroll
    for (int t = 0; t < 8; ++t) {
      int rl = t * 8 + rl0;
      int gr = bm + wr + rl;
      if (gr < M)
        *(float4*)&Oq[(size_t)gr * NDIM + jjbase + coff] = *(float4*)&slab[rl * 64 + coff];
    }
  } else {
    unsigned char* slab8 = (unsigned char*)(smem + wid * 8192);
    unsigned char* dstp = (seg == 1) ? Ok : Ov;
    #pragma unroll
    for (int ni = 0; ni < 4; ++ni) {
      int cl = ni * 16 + (lhi << 2);
      int jj = jjbase + cl;
      float4 bb = *(const float4*)&bias[(jj >> 5) * 96 + seg * 32 + (jj & 31)];
      #pragma unroll
      for (int mi = 0; mi < 4; ++mi) {
        int rl = mi * 16 + l15;
        *(unsigned int*)&slab8[rl * 64 + cl] = pk4_e4m3(
            acc[mi][ni][0] + bb.x, acc[mi][ni][1] + bb.y,
            acc[mi][ni][2] + bb.z, acc[mi][ni][3] + bb.w);
      }
    }
    asm volatile("s_waitcnt lgkmcnt(0)" ::: "memory");
    __builtin_amdgcn_sched_barrier(0);
    int rl0 = lane >> 2, coff = (lane & 3) << 4;
    #pragma unroll
    for (int t = 0; t < 4; ++t) {
      int rl = t * 16 + rl0;
      int gr = bm + wr + rl;
      if (gr < M)
        *(float4*)&dstp[(size_t)gr * NDIM + jjbase + coff] = *(float4*)&slab8[rl * 64 + coff];
    }
  }
}

// ---------- MFMA GEMM (EPI 0 = fp32, 2 = gelu+bf16), coalesced LDS-transpose epilogue ----------
template<int EPI>
__global__ __launch_bounds__(256, 4) void mgemm_k(
    const unsigned short* __restrict__ A1, const unsigned short* __restrict__ A2,
    const unsigned short* __restrict__ Wt, const float* __restrict__ bias,
    float* __restrict__ Cf, unsigned short* __restrict__ Cb,
    int M, int K1, int K, int Ncol, int ldb, int nct)
{
  __shared__ char smem[32768];
  unsigned short* As = (unsigned short*)smem;
  unsigned short* Bs = (unsigned short*)(smem + 16384);
  const int tid = threadIdx.x;
  const int lane = tid & 63;
  const int wid = tid >> 6;

  const int nwg = gridDim.x;
  const int q8 = nwg >> 3, r8 = nwg & 7;
  const int xcd = blockIdx.x & 7, idx8 = blockIdx.x >> 3;
  const int swz = (xcd < r8 ? xcd * (q8 + 1) : r8 * (q8 + 1) + (xcd - r8) * q8) + idx8;
  const int bmt = swz / nct;
  const int bnt = swz - bmt * nct;
  const int bm = bmt * 128;
  const int bn = bnt * 128;

  const int wr = (wid >> 1) << 6;
  const int wc = (wid & 1) << 6;
  const int l15 = lane & 15, lhi = lane >> 4;
  const int srow = lane >> 3;
  const int ssl = (((lane & 7) ^ (lane >> 3)) << 3);

  f32x4 acc[4][4];
  #pragma unroll
  for (int i = 0; i < 4; ++i)
    #pragma unroll
    for (int j = 0; j < 4; ++j) acc[i][j] = (f32x4){0.f, 0.f, 0.f, 0.f};

  for (int k0 = 0; k0 < K; k0 += 64) {
    const unsigned short* Ab;
    int ks;
    if (k0 < K1) { Ab = A1; ks = k0; } else { Ab = A2; ks = k0 - K1; }
    #pragma unroll
    for (int t = 0; t < 4; ++t) {
      int qi = wid * 4 + t;
      const unsigned short* ga = Ab + (size_t)(bm + qi * 8 + srow) * 256 + ks + ssl;
      __builtin_amdgcn_global_load_lds(
          (const __attribute__((address_space(1))) void*)ga,
          (__attribute__((address_space(3))) void*)&As[qi * 512], 16, 0, 0);
      const unsigned short* gb = Wt + (size_t)(bn + qi * 8 + srow) * ldb + k0 + ssl;
      __builtin_amdgcn_global_load_lds(
          (const __attribute__((address_space(1))) void*)gb,
          (__attribute__((address_space(3))) void*)&Bs[qi * 512], 16, 0, 0);
    }
    __syncthreads();
    #pragma unroll
    for (int kk = 0; kk < 64; kk += 32) {
      bf16x8 af[4], bfr[4];
      #pragma unroll
      for (int mi = 0; mi < 4; ++mi) {
        int rA = wr + mi * 16 + l15;
        af[mi] = *(const bf16x8*)&As[rA * 64 + ((((kk >> 3) + lhi) ^ (rA & 7)) << 3)];
      }
      #pragma unroll
      for (int ni = 0; ni < 4; ++ni) {
        int rB = wc + ni * 16 + l15;
        bfr[ni] = *(const bf16x8*)&Bs[rB * 64 + ((((kk >> 3) + lhi) ^ (rB & 7)) << 3)];
      }
      #pragma unroll
      for (int mi = 0; mi < 4; ++mi)
        #pragma unroll
        for (int ni = 0; ni < 4; ++ni)
          acc[mi][ni] = __builtin_amdgcn_mfma_f32_16x16x32_bf16(bfr[ni], af[mi], acc[mi][ni], 0, 0, 0);
    }
    __syncthreads();
  }

  if (EPI == 0) {
    float* slabf = (float*)(smem + wid * 8192);
    #pragma unroll
    for (int half = 0; half < 2; ++half) {
      #pragma unroll
      for (int nj = 0; nj < 2; ++nj) {
        int ni = half * 2 + nj;
        int cl = nj * 16 + (lhi << 2);
        float4 bb = *(const float4*)&bias[bn + wc + half * 32 + cl];
        #pragma unroll
        for (int mi = 0; mi < 4; ++mi) {
          int rl = mi * 16 + l15;
          *(float4*)&slabf[rl * 32 + cl] = make_float4(
              acc[mi][ni][0] + bb.x, acc[mi][ni][1] + bb.y,
              acc[mi][ni][2] + bb.z, acc[mi][ni][3] + bb.w);
        }
      }
      asm volatile("s_waitcnt lgkmcnt(0)" ::: "memory");
      __builtin_amdgcn_sched_barrier(0);
      int rl0 = lane >> 3, coff = (lane & 7) << 2;
      #pragma unroll
      for (int t = 0; t < 8; ++t) {
        int rl = t * 8 + rl0;
        int gr = bm + wr + rl;
        if (gr < M)
          *(float4*)&Cf[(size_t)gr * Ncol + bn + wc + half * 32 + coff] =
              *(float4*)&slabf[rl * 32 + coff];
      }
      if (half == 0) {
        asm volatile("s_waitcnt lgkmcnt(0)" ::: "memory");
        __builtin_amdgcn_sched_barrier(0);
      }
    }
  } else {
    unsigned short* slab = (unsigned short*)(smem + wid * 8192);
    #pragma unroll
    for (int ni = 0; ni < 4; ++ni) {
      int cl = ni * 16 + (lhi << 2);
      float4 bb = *(const float4*)&bias[bn + wc + cl];
      #pragma unroll
      for (int mi = 0; mi < 4; ++mi) {
        int rl = mi * 16 + l15;
        float v0 = acc[mi][ni][0] + bb.x;
        float v1 = acc[mi][ni][1] + bb.y;
        float v2 = acc[mi][ni][2] + bb.z;
        float v3 = acc[mi][ni][3] + bb.w;
        v0 = 0.5f * v0 * (1.0f + erff(v0 * 0.70710678118654752f));
        v1 = 0.5f * v1 * (1.0f + erff(v1 * 0.70710678118654752f));
        v2 = 0.5f * v2 * (1.0f + erff(v2 * 0.70710678118654752f));
        v3 = 0.5f * v3 * (1.0f + erff(v3 * 0.70710678118654752f));
        *(ull*)&slab[rl * 64 + cl] = pk4_bf16(v0, v1, v2, v3);
      }
    }
    asm volatile("s_waitcnt lgkmcnt(0)" ::: "memory");
    __builtin_amdgcn_sched_barrier(0);
    int rl0 = lane >> 3, coff = (lane & 7) << 3;
    #pragma unroll
    for (int t = 0; t < 8; ++t) {
      int rl = t * 8 + rl0;
      int gr = bm + wr + rl;
      if (gr < M)
        *(float4*)&Cb[(size_t)gr * Ncol + bn + wc + coff] = *(float4*)&slab[rl * 64 + coff];
    }
  }
}

extern "C" void kernel_launch(void* const* d_in, const int* in_sizes, int n_in,
                              void* d_out, int out_size, void* d_ws, size_t ws_size,
                              hipStream_t stream) {
  (void)n_in; (void)out_size; (void)ws_size;
  const float* x    = (const float*)d_in[0];
  const int*   src  = (const int*)d_in[1];
  const int*   dst  = (const int*)d_in[2];
  const float* Wqkv = (const float*)d_in[3];
  const float* bqkv = (const float*)d_in[4];
  const float* Wout = (const float*)d_in[5];
  const float* bout = (const float*)d_in[6];
  const float* W1   = (const float*)d_in[7];
  const float* b1   = (const float*)d_in[8];
  const float* W2   = (const float*)d_in[9];
  const float* b2   = (const float*)d_in[10];
  float* out = (float*)d_out;

  const int N = in_sizes[0] / NDIM;   // 50000
  const int E = in_sizes[1];          // 800000
  const int Mp = (N + 127) & ~127;    // 50048
  const int nb = (N + SCB - 1) / SCB;

  char* ws = (char*)d_ws;
  size_t off = 0;
  auto alloc = [&](size_t bytes) -> char* {
    char* p = ws + off;
    off += (bytes + 255) & ~(size_t)255;
    return p;
  };
  unsigned short* xb   = (unsigned short*)alloc((size_t)Mp * NDIM * 2);
  unsigned short* Q    = (unsigned short*)alloc((size_t)Mp * NDIM * 2);
  unsigned short* Kb   = (unsigned short*)alloc((size_t)Mp * NDIM * 2);
  unsigned short* Vb   = (unsigned short*)alloc((size_t)Mp * NDIM * 2);
  unsigned short* wqkvt = (unsigned short*)alloc((size_t)768 * 256 * 2);
  unsigned short* wft   = (unsigned short*)alloc((size_t)256 * 512 * 2);
  unsigned short* w2t   = (unsigned short*)alloc((size_t)256 * 256 * 2);
  float*          bc    = (float*)alloc(256 * 4);
  int* deg    = (int*)alloc((size_t)N * 4);
  int* offs   = (int*)alloc((size_t)(N + 1) * 4);
  int* cursor = (int*)alloc((size_t)N * 4);
  int* ssrc   = (int*)alloc((size_t)E * 4);
  int* bsum   = (int*)alloc((size_t)nb * 4);

  unsigned char* K8 = (unsigned char*)Kb;
  unsigned char* V8 = (unsigned char*)Vb;
  unsigned short* agg = Q;    // attn writes in place over Q
  unsigned short* h1  = Kb;   // Kb dead after attn

  const int n8  = N * NDIM / 8;             // 1.6M
  const int nbx = (n8 + 255) / 256;         // 6250
  const int nbw = (393472 + 255) / 256;     // 1537
  const int nsc = (E + 255) / 256;          // 3125
  const int mt  = Mp / 128;                 // 391

  // deg must be zero before fuse0's hist partition
  hipMemsetAsync(deg, 0, (size_t)N * 4, stream);

  // FUSED: xconv + weight prep + degree histogram
  fuse0_k<<<nbx + nbw + nsc, 256, 0, stream>>>(
      x, xb, n8, nbx, Wqkv, wqkvt, W1, wft, W2, w2t, Wout, bout, b1, bc, nbw,
      dst, deg, E);

  // CSR scan (offs + cursor)
  bsum_k<<<nb, SCB, 0, stream>>>(deg, bsum, N);
  bscan_k<<<1, 128, 0, stream>>>(bsum, nb);
  offs_k<<<nb, SCB, 0, stream>>>(deg, bsum, offs, cursor, N);

  // FUSED: scatter + QKV projection (Q bf16, K8/V8 fp8; wqkvt column-permuted)
  sqkv_k<<<nsc + mt * 6, 256, 0, stream>>>(
      src, dst, cursor, ssrc, E, nsc,
      xb, wqkvt, bqkv, Q, K8, V8, N);

  // edge-softmax aggregation (agg == Q in place)
  attn_k<<<(N + 3) / 4, 256, 0, stream>>>(Q, K8, V8, offs, ssrc, agg, N);

  // FUSED FFN-in: gelu(x@W1a + agg@(Wout@W1b) + bc) -> h1 (bf16)
  mgemm_k<2><<<mt * 2, 256, 0, stream>>>(
      xb, agg, wft, bc, nullptr, h1, N, 256, 512, 256, 512, 2);

  // h1 @ W2 + b2 -> out (fp32)
  mgemm_k<0><<<mt * 2, 256, 0, stream>>>(
      h1, nullptr, w2t, b2, out, nullptr, N, 256, 256, 256, 256, 2);
}

// Round 11
// 220.848 us; speedup vs baseline: 1.3904x; 1.2036x over previous
//
#include <hip/hip_runtime.h>
#include <hip/hip_bf16.h>
#include <math.h>

#define NDIM 256
#define HDIM 32
#define SCB 512

typedef __attribute__((ext_vector_type(8))) short bf16x8;
typedef __attribute__((ext_vector_type(4))) float f32x4;
typedef __attribute__((ext_vector_type(2))) float f32x2;
typedef unsigned long long ull;

// ---------- bf16 helpers ----------
__device__ inline float bf2f(unsigned short u) {
  union { unsigned int i; float f; } c; c.i = ((unsigned int)u) << 16; return c.f;
}
__device__ inline unsigned short f2bf(float f) {
  union { float f; unsigned int i; } c; c.f = f;
  unsigned int x = c.i;
  unsigned int lsb = (x >> 16) & 1u;
  x += 0x7fffu + lsb;
  return (unsigned short)(x >> 16);
}
__device__ inline float4 ldbf4(const unsigned short* p) {
  ull raw = *(const ull*)p;
  float4 f;
  f.x = bf2f((unsigned short)(raw));
  f.y = bf2f((unsigned short)(raw >> 16));
  f.z = bf2f((unsigned short)(raw >> 32));
  f.w = bf2f((unsigned short)(raw >> 48));
  return f;
}
__device__ inline void stbf4(unsigned short* p, float4 v) {
  ull raw = (ull)f2bf(v.x) | ((ull)f2bf(v.y) << 16)
          | ((ull)f2bf(v.z) << 32) | ((ull)f2bf(v.w) << 48);
  *(ull*)p = raw;
}
__device__ inline ull pk4_bf16(float v0, float v1, float v2, float v3) {
  return (ull)f2bf(v0) | ((ull)f2bf(v1) << 16) | ((ull)f2bf(v2) << 32) | ((ull)f2bf(v3) << 48);
}

// ---------- fp8 e4m3 helpers ----------
__device__ inline unsigned char f2e4m3(float v) {
#if __has_builtin(__builtin_amdgcn_cvt_pk_fp8_f32)
  return (unsigned char)(__builtin_amdgcn_cvt_pk_fp8_f32(v, v, 0, false) & 0xff);
#else
  union { float f; unsigned int u; } c; c.f = v;
  unsigned char s = (unsigned char)((c.u >> 24) & 0x80);
  float a = fabsf(v);
  if (!(a < 448.f)) return (unsigned char)(s | 0x7e);
  if (a < 0.0009765625f) return s;
  int e = (int)((c.u >> 23) & 0xff) - 127;
  if (e < -6) {
    int q = (int)rintf(ldexpf(a, 9));
    if (q >= 8) return (unsigned char)(s | 0x08);
    return (unsigned char)(s | q);
  }
  int q = (int)rintf(ldexpf(a, 3 - e));
  if (q == 16) { e++; q = 8; }
  if (e > 8) return (unsigned char)(s | 0x7e);
  return (unsigned char)(s | ((e + 7) << 3) | (q - 8));
#endif
}
__device__ inline unsigned int pk4_e4m3(float v0, float v1, float v2, float v3) {
#if __has_builtin(__builtin_amdgcn_cvt_pk_fp8_f32)
  int w = __builtin_amdgcn_cvt_pk_fp8_f32(v0, v1, 0, false);
  w = __builtin_amdgcn_cvt_pk_fp8_f32(v2, v3, w, true);
  return (unsigned int)w;
#else
  return (unsigned int)f2e4m3(v0) | ((unsigned int)f2e4m3(v1) << 8)
       | ((unsigned int)f2e4m3(v2) << 16) | ((unsigned int)f2e4m3(v3) << 24);
#endif
}
template<bool HI>
__device__ inline f32x2 e4m3pk(unsigned int w) {
#if __has_builtin(__builtin_amdgcn_cvt_pk_f32_fp8)
  return __builtin_amdgcn_cvt_pk_f32_fp8((int)w, HI);
#else
  unsigned int h = HI ? (w >> 16) : w;
  f32x2 r;
  #pragma unroll
  for (int j = 0; j < 2; ++j) {
    unsigned char b = (unsigned char)(h >> (8 * j));
    int e = (b >> 3) & 0xf, mm = b & 7;
    float val = e ? ldexpf((float)(8 + mm), e - 10) : ldexpf((float)mm, -9);
    r[j] = (b & 0x80) ? -val : val;
  }
  return r;
#endif
}

// ---------- FUSED prep: xconv + all weight prep + degree histogram (with edge rank) ----------
__global__ void fuse0_k(
    const float* __restrict__ x, unsigned short* __restrict__ xb, int n8, int nbx,
    const float* __restrict__ Wqkv, unsigned short* __restrict__ wqkvt,
    const float* __restrict__ W1, unsigned short* __restrict__ wf,
    const float* __restrict__ W2, unsigned short* __restrict__ w2t,
    const float* __restrict__ Wout, const float* __restrict__ bout,
    const float* __restrict__ b1, float* __restrict__ bc, int nbw,
    const int* __restrict__ dst, int* __restrict__ deg, int* __restrict__ erank, int E)
{
  int b = blockIdx.x;
  int tid = threadIdx.x;
  if (b < nbx) {
    int i = b * 256 + tid;
    if (i < n8) {
      const float* p = x + (size_t)i * 8;
      float4 a = *(const float4*)p;
      float4 bv = *(const float4*)(p + 4);
      ull lo = (ull)f2bf(a.x) | ((ull)f2bf(a.y) << 16) | ((ull)f2bf(a.z) << 32) | ((ull)f2bf(a.w) << 48);
      ull hi = (ull)f2bf(bv.x) | ((ull)f2bf(bv.y) << 16) | ((ull)f2bf(bv.z) << 32) | ((ull)f2bf(bv.w) << 48);
      ull* d = (ull*)(xb + (size_t)i * 8);
      d[0] = lo; d[1] = hi;
    }
    return;
  }
  b -= nbx;
  if (b < nbw) {
    int idx = b * 256 + tid;
    if (idx < 196608) {
      int j = idx >> 8, k = idx & 255;
      int seg = j >> 8, jj = j & 255;
      int h = jj >> 5, t = jj & 31;
      int orig = h * 96 + seg * 32 + t;
      wqkvt[(size_t)j * 256 + k] = f2bf(Wqkv[(size_t)k * 768 + orig]);
    } else if (idx < 262144) {
      int i2 = idx - 196608;
      int n = i2 >> 8, k = i2 & 255;
      wf[(size_t)n * 512 + k] = f2bf(W1[(size_t)k * 256 + n]);
    } else if (idx < 327680) {
      int i3 = idx - 262144;
      int n = i3 >> 8, k = i3 & 255;
      w2t[(size_t)n * 256 + k] = f2bf(W2[(size_t)k * 256 + n]);
    } else if (idx < 393216) {
      int i4 = idx - 327680;
      int a = i4 >> 8, n = i4 & 255;
      float s = 0.f;
      #pragma unroll 4
      for (int j = 0; j < 256; ++j)
        s += Wout[(size_t)a * 256 + j] * W1[(size_t)(256 + j) * 256 + n];
      wf[(size_t)n * 512 + 256 + a] = f2bf(s);
    } else if (idx < 393472) {
      int n = idx - 393216;
      float s = b1[n];
      for (int j = 0; j < 256; ++j)
        s += bout[j] * W1[(size_t)(256 + j) * 256 + n];
      bc[n] = s;
    }
    return;
  }
  b -= nbw;
  int e = b * 256 + tid;
  if (e < E) {
    int r = atomicAdd(&deg[dst[e]], 1);
    erank[e] = r;
  }
}

// ---------- CSR scan ----------
__global__ __launch_bounds__(SCB) void bsum_k(const int* __restrict__ deg, int* __restrict__ bsum, int n) {
  int tid = threadIdx.x;
  int i = blockIdx.x * SCB + tid;
  int v = (i < n) ? deg[i] : 0;
  #pragma unroll
  for (int d = 1; d < 64; d <<= 1) v += __shfl_xor(v, d);
  __shared__ int wsum[8];
  if ((tid & 63) == 0) wsum[tid >> 6] = v;
  __syncthreads();
  if (tid == 0) {
    int s = 0;
    #pragma unroll
    for (int j = 0; j < 8; ++j) s += wsum[j];
    bsum[blockIdx.x] = s;
  }
}

__global__ __launch_bounds__(128) void bscan_k(int* __restrict__ bsum, int nb) {
  __shared__ int tmp[128];
  int tid = threadIdx.x;
  int v = (tid < nb) ? bsum[tid] : 0;
  tmp[tid] = v;
  __syncthreads();
  for (int d = 1; d < 128; d <<= 1) {
    int t = (tid >= d) ? tmp[tid - d] : 0;
    __syncthreads();
    tmp[tid] += t;
    __syncthreads();
  }
  if (tid < nb) bsum[tid] = tmp[tid];
}

__global__ __launch_bounds__(SCB) void offs_k(const int* __restrict__ deg, const int* __restrict__ bsum,
                                              int* __restrict__ offs, int n) {
  int tid = threadIdx.x, lane = tid & 63, wid = tid >> 6;
  int b = blockIdx.x;
  int i = b * SCB + tid;
  int v = (i < n) ? deg[i] : 0;
  int incl = v;
  #pragma unroll
  for (int d = 1; d < 64; d <<= 1) { int t = __shfl_up(incl, d); if (lane >= d) incl += t; }
  __shared__ int wsum[8];
  if (lane == 63) wsum[wid] = incl;
  __syncthreads();
  if (tid < 8) {
    int s = wsum[tid];
    #pragma unroll
    for (int d = 1; d < 8; d <<= 1) { int t = __shfl_up(s, d); if (tid >= d) s += t; }
    wsum[tid] = s;
  }
  __syncthreads();
  int base = (b > 0 ? bsum[b - 1] : 0) + (wid > 0 ? wsum[wid - 1] : 0);
  if (i < n) offs[i] = base + incl - v;
  if (i == n - 1) offs[n] = base + incl;
}

// ---------- atomic-free scatter: position = offs[dst] + precomputed rank ----------
__global__ void scatter2_k(const int* __restrict__ src, const int* __restrict__ dstv,
                           const int* __restrict__ offs, const int* __restrict__ erank,
                           int* __restrict__ ssrc, int E) {
  int e = blockIdx.x * 256 + threadIdx.x;
  if (e < E) ssrc[offs[dstv[e]] + erank[e]] = src[e];
}

// ---------- per-node softmax attention, fp8 K/V, fixed-shift ----------
__global__ __launch_bounds__(256) void attn_k(
    const unsigned short* Q,
    const unsigned char* __restrict__ K8,
    const unsigned char* __restrict__ V8,
    const int* __restrict__ offs,
    const int* __restrict__ ssrc,
    unsigned short* agg, int N)
{
  int n = blockIdx.x * 4 + (threadIdx.x >> 6);
  if (n >= N) return;
  int lane = threadIdx.x & 63;
  int col = lane << 2;
  const float scale = 0.17677669529663689f;
  float4 q4 = ldbf4(Q + (size_t)n * NDIM + col);
  q4.x *= scale; q4.y *= scale; q4.z *= scale; q4.w *= scale;
  int e0 = offs[n], e1 = offs[n + 1];
  float den = 0.f;
  float ax = 0.f, ay = 0.f, az = 0.f, aw = 0.f;
  int e = e0;
  for (; e + 8 <= e1; e += 8) {
    unsigned int kw[8], vw[8];
    #pragma unroll
    for (int j = 0; j < 8; ++j) {
      int s = ssrc[e + j];
      kw[j] = *(const unsigned int*)(K8 + (size_t)s * NDIM + col);
      vw[j] = *(const unsigned int*)(V8 + (size_t)s * NDIM + col);
    }
    float d[8];
    #pragma unroll
    for (int j = 0; j < 8; ++j) {
      f32x2 k01 = e4m3pk<false>(kw[j]);
      f32x2 k23 = e4m3pk<true>(kw[j]);
      d[j] = q4.x * k01[0] + q4.y * k01[1] + q4.z * k23[0] + q4.w * k23[1];
    }
    #pragma unroll
    for (int j = 0; j < 8; ++j) {
      d[j] += __shfl_xor(d[j], 1);
      d[j] += __shfl_xor(d[j], 2);
      d[j] += __shfl_xor(d[j], 4);
    }
    #pragma unroll
    for (int j = 0; j < 8; ++j) {
      float p = __expf(d[j]);
      den += p;
      f32x2 v01 = e4m3pk<false>(vw[j]);
      f32x2 v23 = e4m3pk<true>(vw[j]);
      ax += p * v01[0]; ay += p * v01[1];
      az += p * v23[0]; aw += p * v23[1];
    }
  }
  for (; e + 4 <= e1; e += 4) {
    unsigned int kw[4], vw[4];
    #pragma unroll
    for (int j = 0; j < 4; ++j) {
      int s = ssrc[e + j];
      kw[j] = *(const unsigned int*)(K8 + (size_t)s * NDIM + col);
      vw[j] = *(const unsigned int*)(V8 + (size_t)s * NDIM + col);
    }
    float d[4];
    #pragma unroll
    for (int j = 0; j < 4; ++j) {
      f32x2 k01 = e4m3pk<false>(kw[j]);
      f32x2 k23 = e4m3pk<true>(kw[j]);
      d[j] = q4.x * k01[0] + q4.y * k01[1] + q4.z * k23[0] + q4.w * k23[1];
    }
    #pragma unroll
    for (int j = 0; j < 4; ++j) {
      d[j] += __shfl_xor(d[j], 1);
      d[j] += __shfl_xor(d[j], 2);
      d[j] += __shfl_xor(d[j], 4);
    }
    #pragma unroll
    for (int j = 0; j < 4; ++j) {
      float p = __expf(d[j]);
      den += p;
      f32x2 v01 = e4m3pk<false>(vw[j]);
      f32x2 v23 = e4m3pk<true>(vw[j]);
      ax += p * v01[0]; ay += p * v01[1];
      az += p * v23[0]; aw += p * v23[1];
    }
  }
  for (; e < e1; ++e) {
    int s = ssrc[e];
    unsigned int kw = *(const unsigned int*)(K8 + (size_t)s * NDIM + col);
    unsigned int vw = *(const unsigned int*)(V8 + (size_t)s * NDIM + col);
    f32x2 k01 = e4m3pk<false>(kw);
    f32x2 k23 = e4m3pk<true>(kw);
    float d = q4.x * k01[0] + q4.y * k01[1] + q4.z * k23[0] + q4.w * k23[1];
    d += __shfl_xor(d, 1);
    d += __shfl_xor(d, 2);
    d += __shfl_xor(d, 4);
    float p = __expf(d);
    den += p;
    f32x2 v01 = e4m3pk<false>(vw);
    f32x2 v23 = e4m3pk<true>(vw);
    ax += p * v01[0]; ay += p * v01[1];
    az += p * v23[0]; aw += p * v23[1];
  }
  float inv = (den > 0.f) ? 1.f / den : 0.f;
  stbf4(agg + (size_t)n * NDIM + col, make_float4(ax * inv, ay * inv, az * inv, aw * inv));
}

// ---------- QKV MFMA GEMM (standalone; swizzled slab epilogue) ----------
__global__ __launch_bounds__(256, 4) void qkv_k(
    const unsigned short* __restrict__ A1, const unsigned short* __restrict__ Wt,
    const float* __restrict__ bias,
    unsigned short* __restrict__ Oq, unsigned char* __restrict__ Ok, unsigned char* __restrict__ Ov,
    int M)
{
  __shared__ char smem[32768];
  unsigned short* As = (unsigned short*)smem;
  unsigned short* Bs = (unsigned short*)(smem + 16384);
  const int tid = threadIdx.x;
  const int lane = tid & 63;
  const int wid = tid >> 6;

  const int nwg = gridDim.x;
  const int q8 = nwg >> 3, r8 = nwg & 7;
  const int xcd = blockIdx.x & 7, idx8 = blockIdx.x >> 3;
  const int swz = (xcd < r8 ? xcd * (q8 + 1) : r8 * (q8 + 1) + (xcd - r8) * q8) + idx8;
  const int nct = 6;
  const int bmt = swz / nct;
  const int bnt = swz - bmt * nct;
  const int bm = bmt * 128;
  const int bn = bnt * 128;

  const int wr = (wid >> 1) << 6;
  const int wc = (wid & 1) << 6;
  const int l15 = lane & 15, lhi = lane >> 4;
  const int srow = lane >> 3;
  const int ssl = (((lane & 7) ^ (lane >> 3)) << 3);

  f32x4 acc[4][4];
  #pragma unroll
  for (int i = 0; i < 4; ++i)
    #pragma unroll
    for (int j = 0; j < 4; ++j) acc[i][j] = (f32x4){0.f, 0.f, 0.f, 0.f};

  for (int k0 = 0; k0 < 256; k0 += 64) {
    #pragma unroll
    for (int t = 0; t < 4; ++t) {
      int qi = wid * 4 + t;
      const unsigned short* ga = A1 + (size_t)(bm + qi * 8 + srow) * 256 + k0 + ssl;
      __builtin_amdgcn_global_load_lds(
          (const __attribute__((address_space(1))) void*)ga,
          (__attribute__((address_space(3))) void*)&As[qi * 512], 16, 0, 0);
      const unsigned short* gb = Wt + (size_t)(bn + qi * 8 + srow) * 256 + k0 + ssl;
      __builtin_amdgcn_global_load_lds(
          (const __attribute__((address_space(1))) void*)gb,
          (__attribute__((address_space(3))) void*)&Bs[qi * 512], 16, 0, 0);
    }
    __syncthreads();
    #pragma unroll
    for (int kk = 0; kk < 64; kk += 32) {
      bf16x8 af[4], bfr[4];
      #pragma unroll
      for (int mi = 0; mi < 4; ++mi) {
        int rA = wr + mi * 16 + l15;
        af[mi] = *(const bf16x8*)&As[rA * 64 + ((((kk >> 3) + lhi) ^ (rA & 7)) << 3)];
      }
      #pragma unroll
      for (int ni = 0; ni < 4; ++ni) {
        int rB = wc + ni * 16 + l15;
        bfr[ni] = *(const bf16x8*)&Bs[rB * 64 + ((((kk >> 3) + lhi) ^ (rB & 7)) << 3)];
      }
      #pragma unroll
      for (int mi = 0; mi < 4; ++mi)
        #pragma unroll
        for (int ni = 0; ni < 4; ++ni)
          acc[mi][ni] = __builtin_amdgcn_mfma_f32_16x16x32_bf16(bfr[ni], af[mi], acc[mi][ni], 0, 0, 0);
    }
    __syncthreads();
  }

  const int seg = (bn + wc) >> 8;
  const int jjbase = (bn + wc) & 255;
  char* slabB = smem + wid * 8192;
  if (seg == 0) {
    // bf16 slab: 64 rows x 128B, XOR-swizzled by (row&7)<<4
    #pragma unroll
    for (int ni = 0; ni < 4; ++ni) {
      int cl = ni * 16 + (lhi << 2);
      int jj = jjbase + cl;
      float4 bb = *(const float4*)&bias[(jj >> 5) * 96 + (jj & 31)];
      #pragma unroll
      for (int mi = 0; mi < 4; ++mi) {
        int rl = mi * 16 + l15;
        *(ull*)&slabB[rl * 128 + ((cl * 2) ^ ((rl & 7) << 4))] = pk4_bf16(
            acc[mi][ni][0] + bb.x, acc[mi][ni][1] + bb.y,
            acc[mi][ni][2] + bb.z, acc[mi][ni][3] + bb.w);
      }
    }
    asm volatile("s_waitcnt lgkmcnt(0)" ::: "memory");
    __builtin_amdgcn_sched_barrier(0);
    int rl0 = lane >> 3, co = (lane & 7) << 4;
    #pragma unroll
    for (int t = 0; t < 8; ++t) {
      int rl = t * 8 + rl0;
      int gr = bm + wr + rl;
      if (gr < M)
        *(float4*)&Oq[(size_t)gr * NDIM + jjbase + (co >> 1)] =
            *(float4*)&slabB[rl * 128 + (co ^ ((rl & 7) << 4))];
    }
  } else {
    // fp8 slab: 64 rows x 64B, XOR-swizzled by (row&3)<<4
    unsigned char* dstp = (seg == 1) ? Ok : Ov;
    #pragma unroll
    for (int ni = 0; ni < 4; ++ni) {
      int cl = ni * 16 + (lhi << 2);
      int jj = jjbase + cl;
      float4 bb = *(const float4*)&bias[(jj >> 5) * 96 + seg * 32 + (jj & 31)];
      #pragma unroll
      for (int mi = 0; mi < 4; ++mi) {
        int rl = mi * 16 + l15;
        *(unsigned int*)&slabB[rl * 64 + (cl ^ ((rl & 3) << 4))] = pk4_e4m3(
            acc[mi][ni][0] + bb.x, acc[mi][ni][1] + bb.y,
            acc[mi][ni][2] + bb.z, acc[mi][ni][3] + bb.w);
      }
    }
    asm volatile("s_waitcnt lgkmcnt(0)" ::: "memory");
    __builtin_amdgcn_sched_barrier(0);
    int rl0 = lane >> 2, co = (lane & 3) << 4;
    #pragma unroll
    for (int t = 0; t < 4; ++t) {
      int rl = t * 16 + rl0;
      int gr = bm + wr + rl;
      if (gr < M)
        *(float4*)&dstp[(size_t)gr * NDIM + jjbase + co] =
            *(float4*)&slabB[rl * 64 + (co ^ ((rl & 3) << 4))];
    }
  }
}

// ---------- MFMA GEMM (EPI 0 = fp32, 2 = gelu+bf16), swizzled-slab coalesced epilogue ----------
template<int EPI>
__global__ __launch_bounds__(256, 4) void mgemm_k(
    const unsigned short* __restrict__ A1, const unsigned short* __restrict__ A2,
    const unsigned short* __restrict__ Wt, const float* __restrict__ bias,
    float* __restrict__ Cf, unsigned short* __restrict__ Cb,
    int M, int K1, int K, int Ncol, int ldb, int nct)
{
  __shared__ char smem[32768];
  unsigned short* As = (unsigned short*)smem;
  unsigned short* Bs = (unsigned short*)(smem + 16384);
  const int tid = threadIdx.x;
  const int lane = tid & 63;
  const int wid = tid >> 6;

  const int nwg = gridDim.x;
  const int q8 = nwg >> 3, r8 = nwg & 7;
  const int xcd = blockIdx.x & 7, idx8 = blockIdx.x >> 3;
  const int swz = (xcd < r8 ? xcd * (q8 + 1) : r8 * (q8 + 1) + (xcd - r8) * q8) + idx8;
  const int bmt = swz / nct;
  const int bnt = swz - bmt * nct;
  const int bm = bmt * 128;
  const int bn = bnt * 128;

  const int wr = (wid >> 1) << 6;
  const int wc = (wid & 1) << 6;
  const int l15 = lane & 15, lhi = lane >> 4;
  const int srow = lane >> 3;
  const int ssl = (((lane & 7) ^ (lane >> 3)) << 3);

  f32x4 acc[4][4];
  #pragma unroll
  for (int i = 0; i < 4; ++i)
    #pragma unroll
    for (int j = 0; j < 4; ++j) acc[i][j] = (f32x4){0.f, 0.f, 0.f, 0.f};

  for (int k0 = 0; k0 < K; k0 += 64) {
    const unsigned short* Ab;
    int ks;
    if (k0 < K1) { Ab = A1; ks = k0; } else { Ab = A2; ks = k0 - K1; }
    #pragma unroll
    for (int t = 0; t < 4; ++t) {
      int qi = wid * 4 + t;
      const unsigned short* ga = Ab + (size_t)(bm + qi * 8 + srow) * 256 + ks + ssl;
      __builtin_amdgcn_global_load_lds(
          (const __attribute__((address_space(1))) void*)ga,
          (__attribute__((address_space(3))) void*)&As[qi * 512], 16, 0, 0);
      const unsigned short* gb = Wt + (size_t)(bn + qi * 8 + srow) * ldb + k0 + ssl;
      __builtin_amdgcn_global_load_lds(
          (const __attribute__((address_space(1))) void*)gb,
          (__attribute__((address_space(3))) void*)&Bs[qi * 512], 16, 0, 0);
    }
    __syncthreads();
    #pragma unroll
    for (int kk = 0; kk < 64; kk += 32) {
      bf16x8 af[4], bfr[4];
      #pragma unroll
      for (int mi = 0; mi < 4; ++mi) {
        int rA = wr + mi * 16 + l15;
        af[mi] = *(const bf16x8*)&As[rA * 64 + ((((kk >> 3) + lhi) ^ (rA & 7)) << 3)];
      }
      #pragma unroll
      for (int ni = 0; ni < 4; ++ni) {
        int rB = wc + ni * 16 + l15;
        bfr[ni] = *(const bf16x8*)&Bs[rB * 64 + ((((kk >> 3) + lhi) ^ (rB & 7)) << 3)];
      }
      #pragma unroll
      for (int mi = 0; mi < 4; ++mi)
        #pragma unroll
        for (int ni = 0; ni < 4; ++ni)
          acc[mi][ni] = __builtin_amdgcn_mfma_f32_16x16x32_bf16(bfr[ni], af[mi], acc[mi][ni], 0, 0, 0);
    }
    __syncthreads();
  }

  char* slabB = smem + wid * 8192;
  if (EPI == 0) {
    // fp32 slab: 64 rows x 128B (32 cols), two halves
    #pragma unroll
    for (int half = 0; half < 2; ++half) {
      #pragma unroll
      for (int nj = 0; nj < 2; ++nj) {
        int ni = half * 2 + nj;
        int cl = nj * 16 + (lhi << 2);
        float4 bb = *(const float4*)&bias[bn + wc + half * 32 + cl];
        #pragma unroll
        for (int mi = 0; mi < 4; ++mi) {
          int rl = mi * 16 + l15;
          *(float4*)&slabB[rl * 128 + ((cl * 4) ^ ((rl & 7) << 4))] = make_float4(
              acc[mi][ni][0] + bb.x, acc[mi][ni][1] + bb.y,
              acc[mi][ni][2] + bb.z, acc[mi][ni][3] + bb.w);
        }
      }
      asm volatile("s_waitcnt lgkmcnt(0)" ::: "memory");
      __builtin_amdgcn_sched_barrier(0);
      int rl0 = lane >> 3, co = (lane & 7) << 4;
      #pragma unroll
      for (int t = 0; t < 8; ++t) {
        int rl = t * 8 + rl0;
        int gr = bm + wr + rl;
        if (gr < M)
          *(float4*)&Cf[(size_t)gr * Ncol + bn + wc + half * 32 + (co >> 2)] =
              *(float4*)&slabB[rl * 128 + (co ^ ((rl & 7) << 4))];
      }
      if (half == 0) {
        asm volatile("s_waitcnt lgkmcnt(0)" ::: "memory");
        __builtin_amdgcn_sched_barrier(0);
      }
    }
  } else {
    // bf16 slab: 64 rows x 128B
    #pragma unroll
    for (int ni = 0; ni < 4; ++ni) {
      int cl = ni * 16 + (lhi << 2);
      float4 bb = *(const float4*)&bias[bn + wc + cl];
      #pragma unroll
      for (int mi = 0; mi < 4; ++mi) {
        int rl = mi * 16 + l15;
        float v0 = acc[mi][ni][0] + bb.x;
        float v1 = acc[mi][ni][1] + bb.y;
        float v2 = acc[mi][ni][2] + bb.z;
        float v3 = acc[mi][ni][3] + bb.w;
        v0 = 0.5f * v0 * (1.0f + erff(v0 * 0.70710678118654752f));
        v1 = 0.5f * v1 * (1.0f + erff(v1 * 0.70710678118654752f));
        v2 = 0.5f * v2 * (1.0f + erff(v2 * 0.70710678118654752f));
        v3 = 0.5f * v3 * (1.0f + erff(v3 * 0.70710678118654752f));
        *(ull*)&slabB[rl * 128 + ((cl * 2) ^ ((rl & 7) << 4))] = pk4_bf16(v0, v1, v2, v3);
      }
    }
    asm volatile("s_waitcnt lgkmcnt(0)" ::: "memory");
    __builtin_amdgcn_sched_barrier(0);
    int rl0 = lane >> 3, co = (lane & 7) << 4;
    #pragma unroll
    for (int t = 0; t < 8; ++t) {
      int rl = t * 8 + rl0;
      int gr = bm + wr + rl;
      if (gr < M)
        *(float4*)&Cb[(size_t)gr * Ncol + bn + wc + (co >> 1)] =
            *(float4*)&slabB[rl * 128 + (co ^ ((rl & 7) << 4))];
    }
  }
}

extern "C" void kernel_launch(void* const* d_in, const int* in_sizes, int n_in,
                              void* d_out, int out_size, void* d_ws, size_t ws_size,
                              hipStream_t stream) {
  (void)n_in; (void)out_size; (void)ws_size;
  const float* x    = (const float*)d_in[0];
  const int*   src  = (const int*)d_in[1];
  const int*   dst  = (const int*)d_in[2];
  const float* Wqkv = (const float*)d_in[3];
  const float* bqkv = (const float*)d_in[4];
  const float* Wout = (const float*)d_in[5];
  const float* bout = (const float*)d_in[6];
  const float* W1   = (const float*)d_in[7];
  const float* b1   = (const float*)d_in[8];
  const float* W2   = (const float*)d_in[9];
  const float* b2   = (const float*)d_in[10];
  float* out = (float*)d_out;

  const int N = in_sizes[0] / NDIM;   // 50000
  const int E = in_sizes[1];          // 800000
  const int Mp = (N + 127) & ~127;    // 50048
  const int nb = (N + SCB - 1) / SCB;

  char* ws = (char*)d_ws;
  size_t off = 0;
  auto alloc = [&](size_t bytes) -> char* {
    char* p = ws + off;
    off += (bytes + 255) & ~(size_t)255;
    return p;
  };
  unsigned short* xb   = (unsigned short*)alloc((size_t)Mp * NDIM * 2);
  unsigned short* Q    = (unsigned short*)alloc((size_t)Mp * NDIM * 2);
  unsigned short* Kb   = (unsigned short*)alloc((size_t)Mp * NDIM * 2);
  unsigned short* Vb   = (unsigned short*)alloc((size_t)Mp * NDIM * 2);
  unsigned short* wqkvt = (unsigned short*)alloc((size_t)768 * 256 * 2);
  unsigned short* wft   = (unsigned short*)alloc((size_t)256 * 512 * 2);
  unsigned short* w2t   = (unsigned short*)alloc((size_t)256 * 256 * 2);
  float*          bc    = (float*)alloc(256 * 4);
  int* deg    = (int*)alloc((size_t)N * 4);
  int* offs   = (int*)alloc((size_t)(N + 1) * 4);
  int* erank  = (int*)alloc((size_t)E * 4);
  int* ssrc   = (int*)alloc((size_t)E * 4);
  int* bsum   = (int*)alloc((size_t)nb * 4);

  unsigned char* K8 = (unsigned char*)Kb;
  unsigned char* V8 = (unsigned char*)Vb;
  unsigned short* agg = Q;    // attn writes in place over Q
  unsigned short* h1  = Kb;   // Kb dead after attn

  const int n8  = N * NDIM / 8;             // 1.6M
  const int nbx = (n8 + 255) / 256;         // 6250
  const int nbw = (393472 + 255) / 256;     // 1537
  const int nsc = (E + 255) / 256;          // 3125
  const int mt  = Mp / 128;                 // 391

  hipMemsetAsync(deg, 0, (size_t)N * 4, stream);

  // FUSED: xconv + weight prep + degree histogram (ranks into erank)
  fuse0_k<<<nbx + nbw + nsc, 256, 0, stream>>>(
      x, xb, n8, nbx, Wqkv, wqkvt, W1, wft, W2, w2t, Wout, bout, b1, bc, nbw,
      dst, deg, erank, E);

  // CSR scan
  bsum_k<<<nb, SCB, 0, stream>>>(deg, bsum, N);
  bscan_k<<<1, 128, 0, stream>>>(bsum, nb);
  offs_k<<<nb, SCB, 0, stream>>>(deg, bsum, offs, N);

  // atomic-free scatter
  scatter2_k<<<nsc, 256, 0, stream>>>(src, dst, offs, erank, ssrc, E);

  // QKV projection (Q bf16, K8/V8 fp8; wqkvt column-permuted)
  qkv_k<<<mt * 6, 256, 0, stream>>>(xb, wqkvt, bqkv, Q, K8, V8, N);

  // edge-softmax aggregation (agg == Q in place)
  attn_k<<<(N + 3) / 4, 256, 0, stream>>>(Q, K8, V8, offs, ssrc, agg, N);

  // FUSED FFN-in: gelu(x@W1a + agg@(Wout@W1b) + bc) -> h1 (bf16)
  mgemm_k<2><<<mt * 2, 256, 0, stream>>>(
      xb, agg, wft, bc, nullptr, h1, N, 256, 512, 256, 512, 2);

  // h1 @ W2 + b2 -> out (fp32)
  mgemm_k<0><<<mt * 2, 256, 0, stream>>>(
      h1, nullptr, w2t, b2, out, nullptr, N, 256, 256, 256, 256, 2);
}